// Round 1
// baseline (1475.165 us; speedup 1.0000x reference)
//
#include <hip/hip_runtime.h>
#include <math.h>

// ---------------- problem constants ----------------
constexpr int B    = 256;
constexpr int M    = 256;
constexpr int A    = 33;
constexpr int NH   = 3;
constexpr int NO   = 100;     // NOUT
constexpr int FIN  = 66;      // 2*S+2
constexpr int OBSD = 17666;   // 5*M+2 + 2*M*S
constexpr int D1   = 770;     // 3*M+2
constexpr int D2G  = 76800;   // M * NH * NO (gat part of concat)

__device__ __forceinline__ float lrelu(float x) { return x > 0.f ? x : 0.01f * x; }
__device__ __forceinline__ float eluf(float x)  { return x > 0.f ? x : expm1f(x); }

// ---------------- K0: adjacency bitmask ----------------
__global__ __launch_bounds__(256) void k_adjmask(const int* __restrict__ adj,
                                                 unsigned* __restrict__ adjm) {
  int w = blockIdx.x * 256 + threadIdx.x;       // 2048 words: [i][8]
  if (w >= M * 8) return;
  int i = w >> 3, wd = w & 7;
  const int* row = adj + i * M + wd * 32;
  unsigned mval = 0;
  #pragma unroll
  for (int bit = 0; bit < 32; ++bit) mval |= (row[bit] > 0 ? 1u : 0u) << bit;
  adjm[w] = mval;
}

// ---------------- K1: Wh[h,b,m,o] = feat[b,m,:] . W_gat[h,:,o] ----------------
// W_gat column cached in registers; feat values are block-uniform -> s_loads.
__global__ __launch_bounds__(128) void k_wh(const float* __restrict__ obs,
                                            const float* __restrict__ Wg,
                                            float* __restrict__ Wh) {
  int b = blockIdx.x, h = blockIdx.y;
  int o = threadIdx.x;                // 128 threads, 100 active
  bool act = o < NO;
  int oc = act ? o : 0;
  float wreg[FIN];
  #pragma unroll
  for (int f = 0; f < FIN; ++f) wreg[f] = Wg[((size_t)h * FIN + f) * NO + oc];
  const float* ob = obs + (size_t)b * OBSD;
  float* whp = Wh + ((size_t)h * B + b) * (size_t)(M * NO);
  for (int m0 = 0; m0 < M; m0 += 4) {
    float acc[4] = {0.f, 0.f, 0.f, 0.f};
    #pragma unroll
    for (int f = 0; f < FIN; ++f) {
      float w = wreg[f];
      #pragma unroll
      for (int q = 0; q < 4; ++q) {
        int mq = m0 + q;
        float fv;
        if (f == 0)       fv = ob[770 + mq];                   // mcs_res
        else if (f == 1)  fv = ob[1026 + mq];                  // mcs_ins
        else if (f < 34)  fv = ob[1282 + mq * 32 + (f - 2)];   // resp
        else              fv = ob[9474 + mq * 32 + (f - 34)];  // insp
        acc[q] += fv * w;
      }
    }
    if (act) {
      #pragma unroll
      for (int q = 0; q < 4; ++q) whp[(size_t)(m0 + q) * NO + o] = acc[q];
    }
  }
}

// ---------------- K2: e1/e2 = Wh . a_gat halves ----------------
__global__ __launch_bounds__(256) void k_e12(const float* __restrict__ Wh,
                                             const float* __restrict__ ag,
                                             float* __restrict__ e1,
                                             float* __restrict__ e2) {
  int b = blockIdx.x, h = blockIdx.y, m = threadIdx.x;
  __shared__ float a1s[NO], a2s[NO];
  if (m < NO) { a1s[m] = ag[h * 200 + m]; a2s[m] = ag[h * 200 + NO + m]; }
  __syncthreads();
  const float* row = Wh + (((size_t)h * B + b) * M + m) * NO;
  float s1 = 0.f, s2 = 0.f;
  #pragma unroll 4
  for (int o = 0; o < NO; ++o) { float w = row[o]; s1 += w * a1s[o]; s2 += w * a2s[o]; }
  size_t idx = ((size_t)h * B + b) * M + m;
  e1[idx] = s1;
  e2[idx] = s2;
}

// ---------------- K3: per-column softmax stats (softmax over axis i!) ----------------
__global__ __launch_bounds__(256) void k_colstats(const float* __restrict__ e1,
                                                  const float* __restrict__ e2,
                                                  const int* __restrict__ adj,
                                                  float* __restrict__ cmax,
                                                  float* __restrict__ csum) {
  int b = blockIdx.x, h = blockIdx.y, j = threadIdx.x;
  __shared__ float e1s[M];
  size_t base = ((size_t)h * B + b) * M;
  e1s[j] = e1[base + j];
  __syncthreads();
  float e2j = e2[base + j];
  float mx = -INFINITY;
  for (int i = 0; i < M; ++i) {
    float v = (adj[i * M + j] > 0) ? lrelu(e1s[i] + e2j) : -9e15f;
    mx = fmaxf(mx, v);
  }
  float sm = 0.f;
  for (int i = 0; i < M; ++i) {
    float v = (adj[i * M + j] > 0) ? lrelu(e1s[i] + e2j) : -9e15f;
    sm += expf(v - mx);   // masked entries underflow to 0, exactly like JAX
  }
  cmax[base + j] = mx;
  csum[base + j] = sm;
}

// ---------------- K4: h_prime = att @ Wh, elu, scatter into feats[B,M,300] --------
// Block = (b,h). att computed on the fly. 2 i-rows/thread so each ds_read_b128
// feeds 8 FMAs. Wh staged in LDS in two 128-row halves, padded 100->104 for
// 16B-aligned float4 reads.
__global__ __launch_bounds__(256) void k_attn(const float* __restrict__ Wh,
                                              const float* __restrict__ e1,
                                              const float* __restrict__ e2,
                                              const float* __restrict__ cmax,
                                              const float* __restrict__ csum,
                                              const unsigned* __restrict__ adjm,
                                              float* __restrict__ feats) {
  int b = blockIdx.x, h = blockIdx.y;
  int t = threadIdx.x;
  int oh = t >> 7;          // o-half: [0..51] / [52..99]
  int ip = t & 127;
  int i0 = ip * 2, i1 = i0 + 1;
  __shared__ float WhT[128 * 104];      // 53248 B
  __shared__ unsigned ams[M * 8];       //  8192 B
  __shared__ float e2s[M], cms[M], csr[M];  // 3072 B  (total 64512 <= 64K)
  size_t base = ((size_t)h * B + b) * M;
  for (int j = t; j < M; j += 256) {
    e2s[j] = e2[base + j];
    cms[j] = cmax[base + j];
    csr[j] = 1.0f / csum[base + j];
  }
  for (int w = t; w < M * 8; w += 256) ams[w] = adjm[w];
  float ei0 = e1[base + i0], ei1 = e1[base + i1];
  float acc0[52], acc1[52];
  #pragma unroll
  for (int q = 0; q < 52; ++q) { acc0[q] = 0.f; acc1[q] = 0.f; }
  const float* WhG = Wh + base * NO;
  for (int jh = 0; jh < 2; ++jh) {
    __syncthreads();
    const float* src = WhG + (size_t)jh * 128 * NO;
    for (int idx = t; idx < 128 * 104; idx += 256) {
      int jj = idx / 104, o = idx % 104;
      WhT[idx] = (o < NO) ? src[jj * NO + o] : 0.f;
    }
    __syncthreads();
    for (int jj = 0; jj < 128; ++jj) {
      int j = jh * 128 + jj;
      unsigned m0b = (ams[i0 * 8 + (j >> 5)] >> (j & 31)) & 1u;
      unsigned m1b = (ams[i1 * 8 + (j >> 5)] >> (j & 31)) & 1u;
      float e2j = e2s[j], cmj = cms[j], rs = csr[j];
      float v0 = m0b ? lrelu(ei0 + e2j) : -9e15f;
      float v1 = m1b ? lrelu(ei1 + e2j) : -9e15f;
      float p0 = expf(v0 - cmj) * rs;
      float p1 = expf(v1 - cmj) * rs;
      const float4* w4 = (const float4*)(WhT + jj * 104 + oh * 52);
      #pragma unroll
      for (int q = 0; q < 13; ++q) {
        float4 wv = w4[q];
        acc0[4*q+0] += p0 * wv.x; acc1[4*q+0] += p1 * wv.x;
        acc0[4*q+1] += p0 * wv.y; acc1[4*q+1] += p1 * wv.y;
        acc0[4*q+2] += p0 * wv.z; acc1[4*q+2] += p1 * wv.z;
        acc0[4*q+3] += p0 * wv.w; acc1[4*q+3] += p1 * wv.w;
      }
    }
  }
  // feats[b, i, h*100 + o]  (moveaxis h to dim 2)
  size_t f0 = ((size_t)b * M + i0) * 300 + h * NO + oh * 52;
  size_t f1 = ((size_t)b * M + i1) * 300 + h * NO + oh * 52;
  #pragma unroll
  for (int q = 0; q < 52; ++q) {
    if (oh * 52 + q < NO) {       // static index; predicated store
      feats[f0 + q] = eluf(acc0[q]);
      feats[f1 + q] = eluf(acc1[q]);
    }
  }
}

// ---------------- K5: LayerNorm(300) + elu, in place ----------------
__global__ __launch_bounds__(128) void k_ln(float* __restrict__ g,
                                            const float* __restrict__ lw,
                                            const float* __restrict__ lb) {
  int r = blockIdx.x, t = threadIdx.x;
  __shared__ float buf[300];
  __shared__ float red[128];
  float* row = g + (size_t)r * 300;
  for (int i = t; i < 300; i += 128) buf[i] = row[i];
  __syncthreads();
  float s = 0.f;
  for (int i = t; i < 300; i += 128) s += buf[i];
  red[t] = s;
  __syncthreads();
  for (int st = 64; st > 0; st >>= 1) {
    if (t < st) red[t] += red[t + st];
    __syncthreads();
  }
  float mu = red[0] / 300.f;
  __syncthreads();
  float ss = 0.f;
  for (int i = t; i < 300; i += 128) { float d = buf[i] - mu; ss += d * d; }
  red[t] = ss;
  __syncthreads();
  for (int st = 64; st > 0; st >>= 1) {
    if (t < st) red[t] += red[t + st];
    __syncthreads();
  }
  float sc = 1.0f / sqrtf(red[0] / 300.f + 1e-5f);
  for (int i = t; i < 300; i += 128) {
    float v = (buf[i] - mu) * sc * lw[i] + lb[i];
    row[i] = eluf(v);
  }
}

// ---------------- K6: server_feat = relu(elu(server_state @ W1 + b1)) ----------------
__global__ __launch_bounds__(128) void k_sf(const float* __restrict__ obs,
                                            const float* __restrict__ W1,
                                            const float* __restrict__ b1,
                                            float* __restrict__ sf) {
  int b = blockIdx.x, t = threadIdx.x;
  __shared__ float ss[D1];
  const float* ob = obs + (size_t)b * OBSD;
  for (int i = t; i < D1; i += 128) ss[i] = ob[i];
  __syncthreads();
  if (t < NO) {
    float acc = 0.f;
    for (int f = 0; f < D1; ++f) acc += ss[f] * W1[(size_t)f * NO + t];
    acc += b1[t];
    sf[b * NO + t] = fmaxf(eluf(acc), 0.f);
  }
}

// ---------------- K7: split-K GEMM  pre[dc,b,k] = gat_tile @ W2[100+,:] --------------
// Grid (8 b-tiles of 32, 64 d-chunks of 1200). Deterministic (no atomics).
__global__ __launch_bounds__(256) void k_gemm2(const float* __restrict__ gat,
                                               const float* __restrict__ W2,
                                               float* __restrict__ pre) {
  int bt = blockIdx.x, dc = blockIdx.y;
  int t = threadIdx.x;
  int k = t & 127, g2 = t >> 7;
  __shared__ float gt[32 * 124];        // +4 pad for aligned float4
  int b0 = bt * 32, d0 = dc * 1200;
  float acc[16];
  #pragma unroll
  for (int r = 0; r < 16; ++r) acc[r] = 0.f;
  for (int ds0 = 0; ds0 < 1200; ds0 += 120) {
    int dsg = d0 + ds0;
    __syncthreads();
    for (int idx = t; idx < 32 * 120; idx += 256) {
      int rr = idx / 120, cc = idx % 120;
      gt[rr * 124 + cc] = gat[(size_t)(b0 + rr) * D2G + dsg + cc];
    }
    __syncthreads();
    const float* w2p = W2 + (size_t)(100 + dsg) * 128 + k;
    for (int c4 = 0; c4 < 30; ++c4) {
      float w0  = w2p[(size_t)(c4 * 4 + 0) * 128];
      float w1  = w2p[(size_t)(c4 * 4 + 1) * 128];
      float w2v = w2p[(size_t)(c4 * 4 + 2) * 128];
      float w3  = w2p[(size_t)(c4 * 4 + 3) * 128];
      #pragma unroll
      for (int r = 0; r < 16; ++r) {
        float4 gv = *(const float4*)(gt + (g2 * 16 + r) * 124 + c4 * 4);
        acc[r] += gv.x * w0 + gv.y * w1 + gv.z * w2v + gv.w * w3;
      }
    }
  }
  #pragma unroll
  for (int r = 0; r < 16; ++r)
    pre[((size_t)dc * B + b0 + g2 * 16 + r) * 128 + k] = acc[r];
}

// ---------------- K8: hidden = relu(elu(server part + split-K partials + b2)) --------
__global__ __launch_bounds__(128) void k_hid(const float* __restrict__ pre,
                                             const float* __restrict__ sf,
                                             const float* __restrict__ W2,
                                             const float* __restrict__ b2,
                                             float* __restrict__ hid) {
  int b = blockIdx.x, k = threadIdx.x;
  float s = 0.f;
  const float* sfb = sf + b * NO;
  for (int f = 0; f < NO; ++f) s += sfb[f] * W2[(size_t)f * 128 + k];
  for (int dc = 0; dc < 64; ++dc) s += pre[((size_t)dc * B + b) * 128 + k];
  s += b2[k];
  hid[(size_t)b * 128 + k] = fmaxf(eluf(s), 0.f);
}

// ---------------- K9: logits -> gumbel one-hot output ----------------
__global__ __launch_bounds__(64) void k_out(const float* __restrict__ hid,
                                            const float* __restrict__ Wout,
                                            const float* __restrict__ bout,
                                            const float* __restrict__ ug,
                                            float* __restrict__ out) {
  int m = blockIdx.x, bt = blockIdx.y, t = threadIdx.x;
  __shared__ float wo[128 * 36];        // padded 33->36 for float4
  __shared__ float hl[64 * 129];        // padded to kill bank conflicts
  for (int idx = t; idx < 128 * 36; idx += 64) {
    int kk = idx / 36, a = idx % 36;
    wo[idx] = (a < A) ? Wout[(size_t)m * 128 * A + kk * A + a] : 0.f;
  }
  int b0 = bt * 64;
  for (int idx = t; idx < 64 * 128; idx += 64) {
    int bb = idx >> 7, kk = idx & 127;
    hl[bb * 129 + kk] = hid[(size_t)(b0 + bb) * 128 + kk];
  }
  __syncthreads();
  int b = b0 + t;
  float l[36];
  #pragma unroll
  for (int a = 0; a < 36; ++a) l[a] = (a < A) ? bout[m * A + a] : 0.f;
  for (int kk = 0; kk < 128; ++kk) {
    float hv = hl[t * 129 + kk];
    const float4* w4 = (const float4*)(wo + kk * 36);
    #pragma unroll
    for (int q = 0; q < 9; ++q) {
      float4 wv = w4[q];
      l[4*q+0] += hv * wv.x;
      l[4*q+1] += hv * wv.y;
      l[4*q+2] += hv * wv.z;
      l[4*q+3] += hv * wv.w;
    }
  }
  const float* ugp = ug + ((size_t)b * M + m) * A;
  float mx = -INFINITY;
  int amx = 0;
  #pragma unroll
  for (int a = 0; a < A; ++a) {
    float th = tanhf(eluf(l[a]));
    float u = ugp[a];
    u = fminf(fmaxf(u, 1e-10f), 1.0f - 1e-10f);  // upper folds to 1.0f, same as JAX f32
    float gb = -logf(-logf(u));
    float z = th + gb;
    l[a] = z;
    if (z > mx) { mx = z; amx = a; }              // strict > == first-index argmax
  }
  float sm = 0.f;
  #pragma unroll
  for (int a = 0; a < A; ++a) { float e = expf(l[a] - mx); l[a] = e; sm += e; }
  float* op = out + ((size_t)b * M + m) * A;
  #pragma unroll
  for (int a = 0; a < A; ++a) {
    float ys = l[a] / sm;
    float yh = (a == amx) ? 1.0f : 0.0f;
    op[a] = (yh + ys) - ys;                       // matches y_hard + y_soft - sg(y_soft)
  }
}

// ---------------- launcher ----------------
extern "C" void kernel_launch(void* const* d_in, const int* in_sizes, int n_in,
                              void* d_out, int out_size, void* d_ws, size_t ws_size,
                              hipStream_t stream) {
  const float* obs  = (const float*)d_in[0];
  const int*   adj  = (const int*)  d_in[1];
  const float* ug   = (const float*)d_in[2];
  const float* Wg   = (const float*)d_in[3];
  const float* ag   = (const float*)d_in[4];
  const float* lw   = (const float*)d_in[5];
  const float* lb   = (const float*)d_in[6];
  const float* W1   = (const float*)d_in[7];
  const float* b1   = (const float*)d_in[8];
  const float* W2   = (const float*)d_in[9];
  const float* b2   = (const float*)d_in[10];
  const float* Wout = (const float*)d_in[11];
  const float* bout = (const float*)d_in[12];
  float* out = (float*)d_out;

  // workspace layout (~161 MiB, all fully written before read; no zero-init needed)
  float* ws = (float*)d_ws;
  size_t off = 0;
  float* Wh    = ws + off; off += (size_t)NH * B * M * NO;   // 19,660,800
  float* feats = ws + off; off += (size_t)B * M * 300;       // 19,660,800
  float* e1    = ws + off; off += (size_t)NH * B * M;
  float* e2    = ws + off; off += (size_t)NH * B * M;
  float* cmx   = ws + off; off += (size_t)NH * B * M;
  float* csm   = ws + off; off += (size_t)NH * B * M;
  float* sf    = ws + off; off += (size_t)B * NO;
  float* pre   = ws + off; off += (size_t)64 * B * 128;
  float* hid   = ws + off; off += (size_t)B * 128;
  unsigned* adjm = (unsigned*)(ws + off);

  k_adjmask <<<dim3(8),      256, 0, stream>>>(adj, adjm);
  k_wh      <<<dim3(B, NH),  128, 0, stream>>>(obs, Wg, Wh);
  k_e12     <<<dim3(B, NH),  256, 0, stream>>>(Wh, ag, e1, e2);
  k_colstats<<<dim3(B, NH),  256, 0, stream>>>(e1, e2, adj, cmx, csm);
  k_attn    <<<dim3(B, NH),  256, 0, stream>>>(Wh, e1, e2, cmx, csm, adjm, feats);
  k_ln      <<<dim3(B * M),  128, 0, stream>>>(feats, lw, lb);
  k_sf      <<<dim3(B),      128, 0, stream>>>(obs, W1, b1, sf);
  k_gemm2   <<<dim3(8, 64),  256, 0, stream>>>(feats, W2, pre);
  k_hid     <<<dim3(B),      128, 0, stream>>>(pre, sf, W2, b2, hid);
  k_out     <<<dim3(M, 4),    64, 0, stream>>>(hid, Wout, bout, ug, out);
}

// Round 2
// 1008.830 us; speedup vs baseline: 1.4623x; 1.4623x over previous
//
#include <hip/hip_runtime.h>
#include <math.h>

// ---------------- problem constants ----------------
constexpr int B    = 256;
constexpr int M    = 256;
constexpr int A    = 33;
constexpr int NH   = 3;
constexpr int NO   = 100;     // NOUT
constexpr int FIN  = 66;      // 2*S+2
constexpr int OBSD = 17666;   // 5*M+2 + 2*M*S
constexpr int D1   = 770;     // 3*M+2
constexpr int D2G  = 76800;   // M * NH * NO (gat part of concat)

__device__ __forceinline__ float lrelu(float x) { return x > 0.f ? x : 0.01f * x; }
__device__ __forceinline__ float eluf(float x)  { return x > 0.f ? x : expm1f(x); }

// ---------------- K0: adjacency bitmask ----------------
__global__ __launch_bounds__(256) void k_adjmask(const int* __restrict__ adj,
                                                 unsigned* __restrict__ adjm) {
  int w = blockIdx.x * 256 + threadIdx.x;       // 2048 words: [i][8]
  if (w >= M * 8) return;
  int i = w >> 3, wd = w & 7;
  const int* row = adj + i * M + wd * 32;
  unsigned mval = 0;
  #pragma unroll
  for (int bit = 0; bit < 32; ++bit) mval |= (row[bit] > 0 ? 1u : 0u) << bit;
  adjm[w] = mval;
}

// ---------------- K1: Wh = feat @ W_gat  (+ fused e1/e2) ----------------
// Block (b,h), 256 threads as 16(to: o-oct) x 16(tm: m-oct). Two 128-m tiles.
// featT[f][m] and W[f][o] staged in LDS; 8x8 register tile -> 64 FMA per
// 4 ds_read_b128 (FMA-bound). e1/e2 = Wh . a_gat halves reduced via LDS tree
// (deterministic), saving the separate k_e12 pass over Wh.
__global__ __launch_bounds__(256) void k_wh(const float* __restrict__ obs,
                                            const float* __restrict__ Wg,
                                            const float* __restrict__ ag,
                                            float* __restrict__ Wh,
                                            float* __restrict__ e1,
                                            float* __restrict__ e2) {
  int b = blockIdx.x, h = blockIdx.y;
  int t = threadIdx.x;
  int to = t >> 4;          // 0..15 -> o = to*8 .. +7 (o<100 valid)
  int tm = t & 15;          // 0..15 -> m-sub = tm*8 .. +7
  __shared__ float smem_w[66 * 104 + 32];   // W[f][o], rows padded to 104, zero slack
  __shared__ float featT[66 * 132];         // featT[f][m], rows padded to 132
  __shared__ float a1s[128], a2s[128];
  const float* ob = obs + (size_t)b * OBSD;

  // stage W (o>=100 zero-padded so padded accs stay finite / contribute 0)
  for (int idx = t; idx < 66 * 104 + 32; idx += 256) {
    float v = 0.f;
    if (idx < 66 * 104) {
      int f = idx / 104, o = idx % 104;
      if (o < NO) v = Wg[((size_t)h * FIN + f) * NO + o];
    }
    smem_w[idx] = v;
  }
  if (t < 128) {
    a1s[t] = (t < NO) ? ag[h * 200 + t] : 0.f;
    a2s[t] = (t < NO) ? ag[h * 200 + NO + t] : 0.f;
  }

  size_t basee = ((size_t)h * B + b) * M;

  for (int tile = 0; tile < 2; ++tile) {
    int m0 = tile * 128;
    // ---- stage featT (coalesced reads, transposed LDS writes) ----
    if (t < 128)       featT[t]               = ob[770  + m0 + t];
    else               featT[132 + (t - 128)] = ob[1026 + m0 + (t - 128)];
    for (int idx = t; idx < 128 * 32; idx += 256) {
      int m = idx >> 5, s = idx & 31;
      featT[(2  + s) * 132 + m] = ob[1282 + (size_t)(m0 + m) * 32 + s];
      featT[(34 + s) * 132 + m] = ob[9474 + (size_t)(m0 + m) * 32 + s];
    }
    __syncthreads();

    // ---- compute 8x8 register tile ----
    float acc[8][8];
    #pragma unroll
    for (int q = 0; q < 8; ++q)
      #pragma unroll
      for (int p = 0; p < 8; ++p) acc[q][p] = 0.f;

    for (int f = 0; f < 66; ++f) {
      const float* fr = featT + f * 132 + tm * 8;
      const float* wr = smem_w + f * 104 + to * 8;
      float4 fa = *(const float4*)fr;
      float4 fb = *(const float4*)(fr + 4);
      float4 wa = *(const float4*)wr;
      float4 wb = *(const float4*)(wr + 4);
      float fm[8] = {fa.x, fa.y, fa.z, fa.w, fb.x, fb.y, fb.z, fb.w};
      float wv[8] = {wa.x, wa.y, wa.z, wa.w, wb.x, wb.y, wb.z, wb.w};
      #pragma unroll
      for (int q = 0; q < 8; ++q)
        #pragma unroll
        for (int p = 0; p < 8; ++p) acc[q][p] += fm[q] * wv[p];
    }
    __syncthreads();   // done reading featT; safe to alias

    // ---- e1/e2 partials into LDS (alias featT region) ----
    float* e1p = featT;              // [128][18]
    float* e2p = featT + 128 * 18;
    #pragma unroll
    for (int q = 0; q < 8; ++q) {
      float p1 = 0.f, p2 = 0.f;
      #pragma unroll
      for (int p = 0; p < 8; ++p) {
        float av = acc[q][p];
        p1 += av * a1s[to * 8 + p];
        p2 += av * a2s[to * 8 + p];
      }
      e1p[(tm * 8 + q) * 18 + to] = p1;
      e2p[(tm * 8 + q) * 18 + to] = p2;
    }

    // ---- Wh global stores (o<100 masked; rows 400B so float4-aligned) ----
    #pragma unroll
    for (int q = 0; q < 8; ++q) {
      int m = m0 + tm * 8 + q;
      float* wp = Wh + (basee + m) * NO + to * 8;
      if (to <= 12) *(float4*)wp       = make_float4(acc[q][0], acc[q][1], acc[q][2], acc[q][3]);
      if (to <= 11) *(float4*)(wp + 4) = make_float4(acc[q][4], acc[q][5], acc[q][6], acc[q][7]);
    }
    __syncthreads();

    // ---- final e reduce ----
    if (t < 128) {
      float s1 = 0.f, s2 = 0.f;
      #pragma unroll
      for (int u = 0; u < 16; ++u) {
        s1 += e1p[t * 18 + u];
        s2 += e2p[t * 18 + u];
      }
      e1[basee + m0 + t] = s1;
      e2[basee + m0 + t] = s2;
    }
    __syncthreads();   // protect aliased region before next tile's stage
  }
}

// ---------------- K3: per-column softmax stats (softmax over axis i!) ----------------
__global__ __launch_bounds__(256) void k_colstats(const float* __restrict__ e1,
                                                  const float* __restrict__ e2,
                                                  const unsigned* __restrict__ adjm,
                                                  float* __restrict__ cmax,
                                                  float* __restrict__ csum) {
  int b = blockIdx.x, h = blockIdx.y, j = threadIdx.x;
  __shared__ float e1s[M];
  __shared__ unsigned ams[M * 8];
  size_t base = ((size_t)h * B + b) * M;
  e1s[j] = e1[base + j];
  for (int w = j; w < M * 8; w += 256) ams[w] = adjm[w];
  __syncthreads();
  float e2j = e2[base + j];
  int jw = j >> 5;
  unsigned jb = 1u << (j & 31);
  float mx = -INFINITY;
  for (int i = 0; i < M; ++i) {
    float v = (ams[i * 8 + jw] & jb) ? lrelu(e1s[i] + e2j) : -9e15f;
    mx = fmaxf(mx, v);
  }
  float sm = 0.f;
  for (int i = 0; i < M; ++i) {
    float v = (ams[i * 8 + jw] & jb) ? lrelu(e1s[i] + e2j) : -9e15f;
    sm += expf(v - mx);   // masked entries underflow to 0, exactly like JAX
  }
  cmax[base + j] = mx;
  csum[base + j] = sm;
}

// ---------------- K4: h_prime = att @ Wh, elu, scatter into feats[B,M,300] --------
__global__ __launch_bounds__(256) void k_attn(const float* __restrict__ Wh,
                                              const float* __restrict__ e1,
                                              const float* __restrict__ e2,
                                              const float* __restrict__ cmax,
                                              const float* __restrict__ csum,
                                              const unsigned* __restrict__ adjm,
                                              float* __restrict__ feats) {
  int b = blockIdx.x, h = blockIdx.y;
  int t = threadIdx.x;
  int oh = t >> 7;          // o-half: [0..51] / [52..99]
  int ip = t & 127;
  int i0 = ip * 2, i1 = i0 + 1;
  __shared__ float WhT[128 * 104];      // 53248 B
  __shared__ unsigned ams[M * 8];       //  8192 B
  __shared__ float e2s[M], cms[M], csr[M];  // 3072 B
  size_t base = ((size_t)h * B + b) * M;
  for (int j = t; j < M; j += 256) {
    e2s[j] = e2[base + j];
    cms[j] = cmax[base + j];
    csr[j] = 1.0f / csum[base + j];
  }
  for (int w = t; w < M * 8; w += 256) ams[w] = adjm[w];
  float ei0 = e1[base + i0], ei1 = e1[base + i1];
  float acc0[52], acc1[52];
  #pragma unroll
  for (int q = 0; q < 52; ++q) { acc0[q] = 0.f; acc1[q] = 0.f; }
  const float* WhG = Wh + base * NO;
  for (int jh = 0; jh < 2; ++jh) {
    __syncthreads();
    const float* src = WhG + (size_t)jh * 128 * NO;
    for (int idx = t; idx < 128 * 104; idx += 256) {
      int jj = idx / 104, o = idx % 104;
      WhT[idx] = (o < NO) ? src[jj * NO + o] : 0.f;
    }
    __syncthreads();
    for (int jj = 0; jj < 128; ++jj) {
      int j = jh * 128 + jj;
      unsigned m0b = (ams[i0 * 8 + (j >> 5)] >> (j & 31)) & 1u;
      unsigned m1b = (ams[i1 * 8 + (j >> 5)] >> (j & 31)) & 1u;
      float e2j = e2s[j], cmj = cms[j], rs = csr[j];
      float v0 = m0b ? lrelu(ei0 + e2j) : -9e15f;
      float v1 = m1b ? lrelu(ei1 + e2j) : -9e15f;
      float p0 = expf(v0 - cmj) * rs;
      float p1 = expf(v1 - cmj) * rs;
      const float4* w4 = (const float4*)(WhT + jj * 104 + oh * 52);
      #pragma unroll
      for (int q = 0; q < 13; ++q) {
        float4 wv = w4[q];
        acc0[4*q+0] += p0 * wv.x; acc1[4*q+0] += p1 * wv.x;
        acc0[4*q+1] += p0 * wv.y; acc1[4*q+1] += p1 * wv.y;
        acc0[4*q+2] += p0 * wv.z; acc1[4*q+2] += p1 * wv.z;
        acc0[4*q+3] += p0 * wv.w; acc1[4*q+3] += p1 * wv.w;
      }
    }
  }
  // feats[b, i, h*100 + o]  (moveaxis h to dim 2)
  size_t f0 = ((size_t)b * M + i0) * 300 + h * NO + oh * 52;
  size_t f1 = ((size_t)b * M + i1) * 300 + h * NO + oh * 52;
  #pragma unroll
  for (int q = 0; q < 52; ++q) {
    if (oh * 52 + q < NO) {
      feats[f0 + q] = eluf(acc0[q]);
      feats[f1 + q] = eluf(acc1[q]);
    }
  }
}

// ---------------- K5: LN stats only (wave per row, shuffle reduce) ----------------
// normalize+elu is applied inside k_gemm2's staging.
__global__ __launch_bounds__(256) void k_lnstats(const float* __restrict__ g,
                                                 float* __restrict__ mu_out,
                                                 float* __restrict__ rs_out) {
  int gid = blockIdx.x * 256 + threadIdx.x;
  int wid = gid >> 6, lane = gid & 63;
  const float* row = g + (size_t)wid * 300;
  float v[5];
  float s = 0.f;
  #pragma unroll
  for (int j = 0; j < 5; ++j) {
    int i = j * 64 + lane;
    v[j] = (i < 300) ? row[i] : 0.f;
    s += v[j];
  }
  #pragma unroll
  for (int d = 1; d < 64; d <<= 1) s += __shfl_xor(s, d);
  float mu = s * (1.f / 300.f);
  float ss = 0.f;
  #pragma unroll
  for (int j = 0; j < 5; ++j) {
    int i = j * 64 + lane;
    float dd = (i < 300) ? (v[j] - mu) : 0.f;
    ss += dd * dd;
  }
  #pragma unroll
  for (int d = 1; d < 64; d <<= 1) ss += __shfl_xor(ss, d);
  if (lane == 0) {
    mu_out[wid] = mu;
    rs_out[wid] = 1.0f / sqrtf(ss * (1.f / 300.f) + 1e-5f);
  }
}

// ---------------- K6: server_feat = relu(elu(server_state @ W1 + b1)) ----------------
__global__ __launch_bounds__(128) void k_sf(const float* __restrict__ obs,
                                            const float* __restrict__ W1,
                                            const float* __restrict__ b1,
                                            float* __restrict__ sf) {
  int b = blockIdx.x, t = threadIdx.x;
  __shared__ float ss[D1];
  const float* ob = obs + (size_t)b * OBSD;
  for (int i = t; i < D1; i += 128) ss[i] = ob[i];
  __syncthreads();
  if (t < NO) {
    float acc = 0.f;
    for (int f = 0; f < D1; ++f) acc += ss[f] * W1[(size_t)f * NO + t];
    acc += b1[t];
    sf[b * NO + t] = fmaxf(eluf(acc), 0.f);
  }
}

// ---------------- K7: split-K GEMM with fused LN+elu on staging ----------------
__global__ __launch_bounds__(256) void k_gemm2(const float* __restrict__ gat,
                                               const float* __restrict__ mu,
                                               const float* __restrict__ rs,
                                               const float* __restrict__ lw,
                                               const float* __restrict__ lb,
                                               const float* __restrict__ W2,
                                               float* __restrict__ pre) {
  int bt = blockIdx.x, dc = blockIdx.y;
  int t = threadIdx.x;
  int k = t & 127, g2 = t >> 7;
  __shared__ float gt[32 * 124];
  int b0 = bt * 32, d0 = dc * 1200;
  float acc[16];
  #pragma unroll
  for (int r = 0; r < 16; ++r) acc[r] = 0.f;
  for (int ds0 = 0; ds0 < 1200; ds0 += 120) {
    int dsg = d0 + ds0;
    __syncthreads();
    for (int idx = t; idx < 32 * 120; idx += 256) {
      int rr = idx / 120, cc = idx % 120;
      int gidx = dsg + cc;
      int brow = b0 + rr;
      int mrow = gidx / 300;
      int d    = gidx - mrow * 300;
      int lrow = brow * M + mrow;
      float x = gat[(size_t)brow * D2G + gidx];
      float val = (x - mu[lrow]) * rs[lrow] * lw[d] + lb[d];
      gt[rr * 124 + cc] = eluf(val);
    }
    __syncthreads();
    const float* w2p = W2 + (size_t)(100 + dsg) * 128 + k;
    for (int c4 = 0; c4 < 30; ++c4) {
      float w0  = w2p[(size_t)(c4 * 4 + 0) * 128];
      float w1  = w2p[(size_t)(c4 * 4 + 1) * 128];
      float w2v = w2p[(size_t)(c4 * 4 + 2) * 128];
      float w3  = w2p[(size_t)(c4 * 4 + 3) * 128];
      #pragma unroll
      for (int r = 0; r < 16; ++r) {
        float4 gv = *(const float4*)(gt + (g2 * 16 + r) * 124 + c4 * 4);
        acc[r] += gv.x * w0 + gv.y * w1 + gv.z * w2v + gv.w * w3;
      }
    }
  }
  #pragma unroll
  for (int r = 0; r < 16; ++r)
    pre[((size_t)dc * B + b0 + g2 * 16 + r) * 128 + k] = acc[r];
}

// ---------------- K8: hidden (+ transposed copy for k_out) ----------------
__global__ __launch_bounds__(128) void k_hid(const float* __restrict__ pre,
                                             const float* __restrict__ sf,
                                             const float* __restrict__ W2,
                                             const float* __restrict__ b2,
                                             float* __restrict__ hid,
                                             float* __restrict__ hidT) {
  int b = blockIdx.x, k = threadIdx.x;
  float s = 0.f;
  const float* sfb = sf + b * NO;
  for (int f = 0; f < NO; ++f) s += sfb[f] * W2[(size_t)f * 128 + k];
  for (int dc = 0; dc < 64; ++dc) s += pre[((size_t)dc * B + b) * 128 + k];
  s += b2[k];
  float v = fmaxf(eluf(s), 0.f);
  hid[(size_t)b * 128 + k] = v;
  hidT[(size_t)k * B + b]  = v;
}

// ---------------- K9: logits -> gumbel one-hot output ----------------
// Block = m (256 threads = one b each). hidT reads coalesced; wo broadcast LDS.
__global__ __launch_bounds__(256) void k_out(const float* __restrict__ hidT,
                                             const float* __restrict__ Wout,
                                             const float* __restrict__ bout,
                                             const float* __restrict__ ug,
                                             float* __restrict__ out) {
  int m = blockIdx.x, b = threadIdx.x;
  __shared__ float wo[128 * 36];        // padded 33->36 for float4
  for (int idx = b; idx < 128 * 36; idx += 256) {
    int kk = idx / 36, a = idx % 36;
    wo[idx] = (a < A) ? Wout[(size_t)m * 128 * A + kk * A + a] : 0.f;
  }
  __syncthreads();
  float l[36];
  #pragma unroll
  for (int a = 0; a < 36; ++a) l[a] = (a < A) ? bout[m * A + a] : 0.f;
  for (int kk = 0; kk < 128; ++kk) {
    float hv = hidT[(size_t)kk * B + b];
    const float4* w4 = (const float4*)(wo + kk * 36);
    #pragma unroll
    for (int q = 0; q < 9; ++q) {
      float4 wv = w4[q];
      l[4*q+0] += hv * wv.x;
      l[4*q+1] += hv * wv.y;
      l[4*q+2] += hv * wv.z;
      l[4*q+3] += hv * wv.w;
    }
  }
  const float* ugp = ug + ((size_t)b * M + m) * A;
  float mx = -INFINITY;
  int amx = 0;
  #pragma unroll
  for (int a = 0; a < A; ++a) {
    float th = tanhf(eluf(l[a]));
    float u = ugp[a];
    u = fminf(fmaxf(u, 1e-10f), 1.0f - 1e-10f);
    float gb = -logf(-logf(u));
    float z = th + gb;
    l[a] = z;
    if (z > mx) { mx = z; amx = a; }
  }
  float sm = 0.f;
  #pragma unroll
  for (int a = 0; a < A; ++a) { float e = expf(l[a] - mx); l[a] = e; sm += e; }
  float* op = out + ((size_t)b * M + m) * A;
  #pragma unroll
  for (int a = 0; a < A; ++a) {
    float ys = l[a] / sm;
    float yh = (a == amx) ? 1.0f : 0.0f;
    op[a] = (yh + ys) - ys;
  }
}

// ---------------- launcher ----------------
extern "C" void kernel_launch(void* const* d_in, const int* in_sizes, int n_in,
                              void* d_out, int out_size, void* d_ws, size_t ws_size,
                              hipStream_t stream) {
  const float* obs  = (const float*)d_in[0];
  const int*   adj  = (const int*)  d_in[1];
  const float* ug   = (const float*)d_in[2];
  const float* Wg   = (const float*)d_in[3];
  const float* ag   = (const float*)d_in[4];
  const float* lw   = (const float*)d_in[5];
  const float* lb   = (const float*)d_in[6];
  const float* W1   = (const float*)d_in[7];
  const float* b1   = (const float*)d_in[8];
  const float* W2   = (const float*)d_in[9];
  const float* b2   = (const float*)d_in[10];
  const float* Wout = (const float*)d_in[11];
  const float* bout = (const float*)d_in[12];
  float* out = (float*)d_out;

  float* ws = (float*)d_ws;
  size_t off = 0;
  float* Wh    = ws + off; off += (size_t)NH * B * M * NO;   // 19,660,800
  float* feats = ws + off; off += (size_t)B * M * 300;       // 19,660,800
  float* e1    = ws + off; off += (size_t)NH * B * M;
  float* e2    = ws + off; off += (size_t)NH * B * M;
  float* cmx   = ws + off; off += (size_t)NH * B * M;
  float* csm   = ws + off; off += (size_t)NH * B * M;
  float* sf    = ws + off; off += (size_t)B * NO;
  float* pre   = ws + off; off += (size_t)64 * B * 128;
  float* hid   = ws + off; off += (size_t)B * 128;
  float* hidT  = ws + off; off += (size_t)B * 128;
  float* muA   = ws + off; off += (size_t)B * M;
  float* rsA   = ws + off; off += (size_t)B * M;
  unsigned* adjm = (unsigned*)(ws + off);

  k_adjmask <<<dim3(8),       256, 0, stream>>>(adj, adjm);
  k_wh      <<<dim3(B, NH),   256, 0, stream>>>(obs, Wg, ag, Wh, e1, e2);
  k_colstats<<<dim3(B, NH),   256, 0, stream>>>(e1, e2, adjm, cmx, csm);
  k_attn    <<<dim3(B, NH),   256, 0, stream>>>(Wh, e1, e2, cmx, csm, adjm, feats);
  k_lnstats <<<dim3(B * M / 4), 256, 0, stream>>>(feats, muA, rsA);
  k_sf      <<<dim3(B),       128, 0, stream>>>(obs, W1, b1, sf);
  k_gemm2   <<<dim3(8, 64),   256, 0, stream>>>(feats, muA, rsA, lw, lb, W2, pre);
  k_hid     <<<dim3(B),       128, 0, stream>>>(pre, sf, W2, b2, hid, hidT);
  k_out     <<<dim3(M),       256, 0, stream>>>(hidT, Wout, bout, ug, out);
}

// Round 4
// 801.197 us; speedup vs baseline: 1.8412x; 1.2592x over previous
//
#include <hip/hip_runtime.h>
#include <math.h>

// ---------------- problem constants ----------------
constexpr int B    = 256;
constexpr int M    = 256;
constexpr int A    = 33;
constexpr int NH   = 3;
constexpr int NO   = 100;     // NOUT
constexpr int FIN  = 66;      // 2*S+2
constexpr int OBSD = 17666;   // 5*M+2 + 2*M*S
constexpr int D1   = 770;     // 3*M+2
constexpr int D2G  = 76800;   // M * NH * NO (gat part of concat)

__device__ __forceinline__ float lrelu(float x) { return x > 0.f ? x : 0.01f * x; }
__device__ __forceinline__ float eluf(float x)  { return x > 0.f ? x : expm1f(x); }

// ---------------- K0: adjacency bitmask ----------------
__global__ __launch_bounds__(256) void k_adjmask(const int* __restrict__ adj,
                                                 unsigned* __restrict__ adjm) {
  int w = blockIdx.x * 256 + threadIdx.x;       // 2048 words: [i][8]
  if (w >= M * 8) return;
  int i = w >> 3, wd = w & 7;
  const int* row = adj + i * M + wd * 32;
  unsigned mval = 0;
  #pragma unroll
  for (int bit = 0; bit < 32; ++bit) mval |= (row[bit] > 0 ? 1u : 0u) << bit;
  adjm[w] = mval;
}

// ---------------- K1: Wh = feat @ W_gat  (+ fused e1/e2) ----------------
__global__ __launch_bounds__(256) void k_wh(const float* __restrict__ obs,
                                            const float* __restrict__ Wg,
                                            const float* __restrict__ ag,
                                            float* __restrict__ Wh,
                                            float* __restrict__ e1,
                                            float* __restrict__ e2) {
  int b = blockIdx.x, h = blockIdx.y;
  int t = threadIdx.x;
  int to = t >> 4;          // 0..15 -> o = to*8 .. +7 (o<100 valid)
  int tm = t & 15;          // 0..15 -> m-sub = tm*8 .. +7
  __shared__ float smem_w[66 * 104 + 32];   // W[f][o], rows padded to 104
  __shared__ float featT[66 * 132];         // featT[f][m], rows padded to 132
  __shared__ float a1s[128], a2s[128];
  const float* ob = obs + (size_t)b * OBSD;

  for (int idx = t; idx < 66 * 104 + 32; idx += 256) {
    float v = 0.f;
    if (idx < 66 * 104) {
      int f = idx / 104, o = idx % 104;
      if (o < NO) v = Wg[((size_t)h * FIN + f) * NO + o];
    }
    smem_w[idx] = v;
  }
  if (t < 128) {
    a1s[t] = (t < NO) ? ag[h * 200 + t] : 0.f;
    a2s[t] = (t < NO) ? ag[h * 200 + NO + t] : 0.f;
  }

  size_t basee = ((size_t)h * B + b) * M;

  for (int tile = 0; tile < 2; ++tile) {
    int m0 = tile * 128;
    if (t < 128)       featT[t]               = ob[770  + m0 + t];
    else               featT[132 + (t - 128)] = ob[1026 + m0 + (t - 128)];
    for (int idx = t; idx < 128 * 32; idx += 256) {
      int m = idx >> 5, s = idx & 31;
      featT[(2  + s) * 132 + m] = ob[1282 + (size_t)(m0 + m) * 32 + s];
      featT[(34 + s) * 132 + m] = ob[9474 + (size_t)(m0 + m) * 32 + s];
    }
    __syncthreads();

    float acc[8][8];
    #pragma unroll
    for (int q = 0; q < 8; ++q)
      #pragma unroll
      for (int p = 0; p < 8; ++p) acc[q][p] = 0.f;

    for (int f = 0; f < 66; ++f) {
      const float* fr = featT + f * 132 + tm * 8;
      const float* wr = smem_w + f * 104 + to * 8;
      float4 fa = *(const float4*)fr;
      float4 fb = *(const float4*)(fr + 4);
      float4 wa = *(const float4*)wr;
      float4 wb = *(const float4*)(wr + 4);
      float fm[8] = {fa.x, fa.y, fa.z, fa.w, fb.x, fb.y, fb.z, fb.w};
      float wv[8] = {wa.x, wa.y, wa.z, wa.w, wb.x, wb.y, wb.z, wb.w};
      #pragma unroll
      for (int q = 0; q < 8; ++q)
        #pragma unroll
        for (int p = 0; p < 8; ++p) acc[q][p] += fm[q] * wv[p];
    }
    __syncthreads();

    float* e1p = featT;              // [128][18]
    float* e2p = featT + 128 * 18;
    #pragma unroll
    for (int q = 0; q < 8; ++q) {
      float p1 = 0.f, p2 = 0.f;
      #pragma unroll
      for (int p = 0; p < 8; ++p) {
        float av = acc[q][p];
        p1 += av * a1s[to * 8 + p];
        p2 += av * a2s[to * 8 + p];
      }
      e1p[(tm * 8 + q) * 18 + to] = p1;
      e2p[(tm * 8 + q) * 18 + to] = p2;
    }

    #pragma unroll
    for (int q = 0; q < 8; ++q) {
      int m = m0 + tm * 8 + q;
      float* wp = Wh + (basee + m) * NO + to * 8;
      if (to <= 12) *(float4*)wp       = make_float4(acc[q][0], acc[q][1], acc[q][2], acc[q][3]);
      if (to <= 11) *(float4*)(wp + 4) = make_float4(acc[q][4], acc[q][5], acc[q][6], acc[q][7]);
    }
    __syncthreads();

    if (t < 128) {
      float s1 = 0.f, s2 = 0.f;
      #pragma unroll
      for (int u = 0; u < 16; ++u) {
        s1 += e1p[t * 18 + u];
        s2 += e2p[t * 18 + u];
      }
      e1[basee + m0 + t] = s1;
      e2[basee + m0 + t] = s2;
    }
    __syncthreads();
  }
}

// ---------------- K3: per-column softmax stats (softmax over axis i!) ----------------
__global__ __launch_bounds__(256) void k_colstats(const float* __restrict__ e1,
                                                  const float* __restrict__ e2,
                                                  const unsigned* __restrict__ adjm,
                                                  float* __restrict__ cmax,
                                                  float* __restrict__ csum) {
  int b = blockIdx.x, h = blockIdx.y, j = threadIdx.x;
  __shared__ float e1s[M];
  __shared__ unsigned ams[M * 8];
  size_t base = ((size_t)h * B + b) * M;
  e1s[j] = e1[base + j];
  for (int w = j; w < M * 8; w += 256) ams[w] = adjm[w];
  __syncthreads();
  float e2j = e2[base + j];
  int jw = j >> 5;
  unsigned jb = 1u << (j & 31);
  float mx = -INFINITY;
  for (int i = 0; i < M; ++i) {
    float v = (ams[i * 8 + jw] & jb) ? lrelu(e1s[i] + e2j) : -9e15f;
    mx = fmaxf(mx, v);
  }
  float sm = 0.f;
  for (int i = 0; i < M; ++i) {
    float v = (ams[i * 8 + jw] & jb) ? lrelu(e1s[i] + e2j) : -9e15f;
    sm += expf(v - mx);
  }
  cmax[base + j] = mx;
  csum[base + j] = sm;
}

// ---------------- K4: h_prime = att @ Wh, elu -> feats[B,M,300] ----------------
// Grid (b, h, os). 256 threads = 1 i-row each. 50 o-columns per block.
// Masks in registers (no LDS conflicts); acc[52] keeps VGPR < 128;
// LDS ~30KB -> 4-5 blocks/CU; epilogue transposes through LDS so global
// stores are contiguous runs.
__global__ __launch_bounds__(256) void k_attn(const float* __restrict__ Wh,
                                              const float* __restrict__ e1,
                                              const float* __restrict__ e2,
                                              const float* __restrict__ cmax,
                                              const float* __restrict__ csum,
                                              const unsigned* __restrict__ adjm,
                                              float* __restrict__ feats) {
  int b = blockIdx.x, h = blockIdx.y, os = blockIdx.z;
  int t = threadIdx.x;                 // i-row
  int o0 = os * 50;
  __shared__ float WhT[128 * 52];      // 26624 B, one j-half at a time
  __shared__ float e2s[M], cms[M], csr[M];
  size_t base = ((size_t)h * B + b) * M;

  e2s[t] = e2[base + t];
  cms[t] = cmax[base + t];
  csr[t] = 1.0f / csum[base + t];

  unsigned mrow[8];
  #pragma unroll
  for (int w = 0; w < 8; ++w) mrow[w] = adjm[t * 8 + w];
  float ei = e1[base + t];

  float acc[52];
  #pragma unroll
  for (int q = 0; q < 52; ++q) acc[q] = 0.f;

  const float* WhG = Wh + base * NO;
  for (int jh = 0; jh < 2; ++jh) {
    __syncthreads();
    const float* src = WhG + (size_t)jh * 128 * NO + o0;
    for (int idx = t; idx < 128 * 52; idx += 256) {
      int jj = idx / 52, o = idx - jj * 52;
      WhT[idx] = (o < 50) ? src[(size_t)jj * NO + o] : 0.f;
    }
    __syncthreads();
    for (int jj = 0; jj < 128; ++jj) {
      int j = jh * 128 + jj;
      unsigned bit = (mrow[j >> 5] >> (j & 31)) & 1u;
      float v = bit ? lrelu(ei + e2s[j]) : -9e15f;
      float p = expf(v - cms[j]) * csr[j];
      const float4* w4 = (const float4*)(WhT + jj * 52);
      #pragma unroll
      for (int q = 0; q < 13; ++q) {
        float4 wv = w4[q];
        acc[4*q+0] += p * wv.x;
        acc[4*q+1] += p * wv.y;
        acc[4*q+2] += p * wv.z;
        acc[4*q+3] += p * wv.w;
      }
    }
  }

  // epilogue: transpose via LDS, coalesced stores
  for (int chunk = 0; chunk < 2; ++chunk) {
    __syncthreads();
    if ((t >> 7) == chunk) {
      float* dst = WhT + (t & 127) * 52;
      #pragma unroll
      for (int q = 0; q < 50; ++q) dst[q] = acc[q];
    }
    __syncthreads();
    for (int idx = t; idx < 128 * 50; idx += 256) {
      int r = idx / 50, o = idx - r * 50;
      feats[((size_t)b * M + chunk * 128 + r) * 300 + h * NO + o0 + o] =
          eluf(WhT[r * 52 + o]);
    }
  }
}

// ---------------- K5: LN stats only (wave per row, shuffle reduce) ----------------
__global__ __launch_bounds__(256) void k_lnstats(const float* __restrict__ g,
                                                 float* __restrict__ mu_out,
                                                 float* __restrict__ rs_out) {
  int gid = blockIdx.x * 256 + threadIdx.x;
  int wid = gid >> 6, lane = gid & 63;
  const float* row = g + (size_t)wid * 300;
  float v[5];
  float s = 0.f;
  #pragma unroll
  for (int j = 0; j < 5; ++j) {
    int i = j * 64 + lane;
    v[j] = (i < 300) ? row[i] : 0.f;
    s += v[j];
  }
  #pragma unroll
  for (int d = 1; d < 64; d <<= 1) s += __shfl_xor(s, d);
  float mu = s * (1.f / 300.f);
  float ss = 0.f;
  #pragma unroll
  for (int j = 0; j < 5; ++j) {
    int i = j * 64 + lane;
    float dd = (i < 300) ? (v[j] - mu) : 0.f;
    ss += dd * dd;
  }
  #pragma unroll
  for (int d = 1; d < 64; d <<= 1) ss += __shfl_xor(ss, d);
  if (lane == 0) {
    mu_out[wid] = mu;
    rs_out[wid] = 1.0f / sqrtf(ss * (1.f / 300.f) + 1e-5f);
  }
}

// ---------------- K6: server_feat, split-F for ILP ----------------
__global__ __launch_bounds__(256) void k_sf(const float* __restrict__ obs,
                                            const float* __restrict__ W1,
                                            const float* __restrict__ b1,
                                            float* __restrict__ sf) {
  int b = blockIdx.x, t = threadIdx.x;
  int k = t & 127, fc = t >> 7;
  __shared__ float ss[D1];
  __shared__ float red[256];
  const float* ob = obs + (size_t)b * OBSD;
  for (int i = t; i < D1; i += 256) ss[i] = ob[i];
  __syncthreads();
  float acc = 0.f;
  if (k < NO) {
    int f0 = fc * 385;
    #pragma unroll 8
    for (int f = f0; f < f0 + 385; ++f) acc += ss[f] * W1[(size_t)f * NO + k];
  }
  red[t] = acc;
  __syncthreads();
  if (t < 128 && k < NO) {
    float v = red[t] + red[t + 128] + b1[k];
    sf[b * NO + k] = fmaxf(eluf(v), 0.f);
  }
}

// ---------------- K7: split-K GEMM with fused LN+elu on staging ----------------
// Grid (16 b-tiles of 16 rows, 64 d-chunks of 1200) -> 1024 blocks, 4 waves/SIMD.
__global__ __launch_bounds__(256) void k_gemm2(const float* __restrict__ gat,
                                               const float* __restrict__ mu,
                                               const float* __restrict__ rs,
                                               const float* __restrict__ lw,
                                               const float* __restrict__ lb,
                                               const float* __restrict__ W2,
                                               float* __restrict__ pre) {
  int bt = blockIdx.x, dc = blockIdx.y;
  int t = threadIdx.x;
  int k = t & 127, g2 = t >> 7;
  __shared__ float gt[16 * 124];
  int b0 = bt * 16, d0 = dc * 1200;
  float acc[8];
  #pragma unroll
  for (int r = 0; r < 8; ++r) acc[r] = 0.f;
  for (int ds0 = 0; ds0 < 1200; ds0 += 120) {
    int dsg = d0 + ds0;
    __syncthreads();
    for (int idx = t; idx < 16 * 120; idx += 256) {
      int rr = idx / 120, cc = idx - rr * 120;
      int gidx = dsg + cc;
      int brow = b0 + rr;
      int mrow = gidx / 300;
      int d    = gidx - mrow * 300;
      int lrow = brow * M + mrow;
      float x = gat[(size_t)brow * D2G + gidx];
      float val = (x - mu[lrow]) * rs[lrow] * lw[d] + lb[d];
      gt[rr * 124 + cc] = eluf(val);
    }
    __syncthreads();
    const float* w2p = W2 + (size_t)(100 + dsg) * 128 + k;
    for (int c4 = 0; c4 < 30; ++c4) {
      float w0  = w2p[(size_t)(c4 * 4 + 0) * 128];
      float w1  = w2p[(size_t)(c4 * 4 + 1) * 128];
      float w2v = w2p[(size_t)(c4 * 4 + 2) * 128];
      float w3  = w2p[(size_t)(c4 * 4 + 3) * 128];
      #pragma unroll
      for (int r = 0; r < 8; ++r) {
        float4 gv = *(const float4*)(gt + (g2 * 8 + r) * 124 + c4 * 4);
        acc[r] += gv.x * w0 + gv.y * w1 + gv.z * w2v + gv.w * w3;
      }
    }
  }
  #pragma unroll
  for (int r = 0; r < 8; ++r)
    pre[((size_t)dc * B + b0 + g2 * 8 + r) * 128 + k] = acc[r];
}

// ---------------- K8: hidden (+ transposed copy), split-DC ----------------
__global__ __launch_bounds__(256) void k_hid(const float* __restrict__ pre,
                                             const float* __restrict__ sf,
                                             const float* __restrict__ W2,
                                             const float* __restrict__ b2,
                                             float* __restrict__ hid,
                                             float* __restrict__ hidT) {
  int b = blockIdx.x, t = threadIdx.x;
  int k = t & 127, p = t >> 7;
  __shared__ float red[256];
  float s = 0.f;
  const float* sfb = sf + b * NO;
  #pragma unroll 4
  for (int dc = p * 32; dc < p * 32 + 32; ++dc)
    s += pre[((size_t)dc * B + b) * 128 + k];
  #pragma unroll 4
  for (int f = p * 50; f < p * 50 + 50; ++f)
    s += sfb[f] * W2[(size_t)f * 128 + k];
  red[t] = s;
  __syncthreads();
  if (t < 128) {
    float v = red[t] + red[t + 128] + b2[k];
    v = fmaxf(eluf(v), 0.f);
    hid[(size_t)b * 128 + k] = v;
    hidT[(size_t)k * B + b]  = v;
  }
}

// ---------------- K9: logits -> gumbel one-hot output ----------------
__global__ __launch_bounds__(256) void k_out(const float* __restrict__ hidT,
                                             const float* __restrict__ Wout,
                                             const float* __restrict__ bout,
                                             const float* __restrict__ ug,
                                             float* __restrict__ out) {
  int m = blockIdx.x, b = threadIdx.x;
  __shared__ float wo[128 * 36];
  for (int idx = b; idx < 128 * 36; idx += 256) {
    int kk = idx / 36, a = idx % 36;
    wo[idx] = (a < A) ? Wout[(size_t)m * 128 * A + kk * A + a] : 0.f;
  }
  __syncthreads();
  float l[36];
  #pragma unroll
  for (int a = 0; a < 36; ++a) l[a] = (a < A) ? bout[m * A + a] : 0.f;
  for (int kk = 0; kk < 128; ++kk) {
    float hv = hidT[(size_t)kk * B + b];
    const float4* w4 = (const float4*)(wo + kk * 36);
    #pragma unroll
    for (int q = 0; q < 9; ++q) {
      float4 wv = w4[q];
      l[4*q+0] += hv * wv.x;
      l[4*q+1] += hv * wv.y;
      l[4*q+2] += hv * wv.z;
      l[4*q+3] += hv * wv.w;
    }
  }
  const float* ugp = ug + ((size_t)b * M + m) * A;
  float mx = -INFINITY;
  int amx = 0;
  #pragma unroll
  for (int a = 0; a < A; ++a) {
    float th = tanhf(eluf(l[a]));
    float u = ugp[a];
    u = fminf(fmaxf(u, 1e-10f), 1.0f - 1e-10f);
    float gb = -logf(-logf(u));
    float z = th + gb;
    l[a] = z;
    if (z > mx) { mx = z; amx = a; }
  }
  float sm = 0.f;
  #pragma unroll
  for (int a = 0; a < A; ++a) { float e = expf(l[a] - mx); l[a] = e; sm += e; }
  float* op = out + ((size_t)b * M + m) * A;
  #pragma unroll
  for (int a = 0; a < A; ++a) {
    float ys = l[a] / sm;
    float yh = (a == amx) ? 1.0f : 0.0f;
    op[a] = (yh + ys) - ys;
  }
}

// ---------------- launcher ----------------
extern "C" void kernel_launch(void* const* d_in, const int* in_sizes, int n_in,
                              void* d_out, int out_size, void* d_ws, size_t ws_size,
                              hipStream_t stream) {
  const float* obs  = (const float*)d_in[0];
  const int*   adj  = (const int*)  d_in[1];
  const float* ug   = (const float*)d_in[2];
  const float* Wg   = (const float*)d_in[3];
  const float* ag   = (const float*)d_in[4];
  const float* lw   = (const float*)d_in[5];
  const float* lb   = (const float*)d_in[6];
  const float* W1   = (const float*)d_in[7];
  const float* b1   = (const float*)d_in[8];
  const float* W2   = (const float*)d_in[9];
  const float* b2   = (const float*)d_in[10];
  const float* Wout = (const float*)d_in[11];
  const float* bout = (const float*)d_in[12];
  float* out = (float*)d_out;

  float* ws = (float*)d_ws;
  size_t off = 0;
  float* Wh    = ws + off; off += (size_t)NH * B * M * NO;   // 19,660,800
  float* feats = ws + off; off += (size_t)B * M * 300;       // 19,660,800
  float* e1    = ws + off; off += (size_t)NH * B * M;
  float* e2    = ws + off; off += (size_t)NH * B * M;
  float* cmx   = ws + off; off += (size_t)NH * B * M;
  float* csm   = ws + off; off += (size_t)NH * B * M;
  float* sf    = ws + off; off += (size_t)B * NO;
  float* pre   = ws + off; off += (size_t)64 * B * 128;
  float* hid   = ws + off; off += (size_t)B * 128;
  float* hidT  = ws + off; off += (size_t)B * 128;
  float* muA   = ws + off; off += (size_t)B * M;
  float* rsA   = ws + off; off += (size_t)B * M;
  unsigned* adjm = (unsigned*)(ws + off);

  k_adjmask <<<dim3(8),         256, 0, stream>>>(adj, adjm);
  k_wh      <<<dim3(B, NH),     256, 0, stream>>>(obs, Wg, ag, Wh, e1, e2);
  k_colstats<<<dim3(B, NH),     256, 0, stream>>>(e1, e2, adjm, cmx, csm);
  k_attn    <<<dim3(B, NH, 2),  256, 0, stream>>>(Wh, e1, e2, cmx, csm, adjm, feats);
  k_lnstats <<<dim3(B * M / 4), 256, 0, stream>>>(feats, muA, rsA);
  k_sf      <<<dim3(B),         256, 0, stream>>>(obs, W1, b1, sf);
  k_gemm2   <<<dim3(16, 64),    256, 0, stream>>>(feats, muA, rsA, lw, lb, W2, pre);
  k_hid     <<<dim3(B),         256, 0, stream>>>(pre, sf, W2, b2, hid, hidT);
  k_out     <<<dim3(M),         256, 0, stream>>>(hidT, Wout, bout, ug, out);
}

// Round 5
// 798.285 us; speedup vs baseline: 1.8479x; 1.0036x over previous
//
#include <hip/hip_runtime.h>
#include <math.h>

// ---------------- problem constants ----------------
constexpr int B    = 256;
constexpr int M    = 256;
constexpr int A    = 33;
constexpr int NH   = 3;
constexpr int NO   = 100;     // NOUT
constexpr int FIN  = 66;      // 2*S+2
constexpr int OBSD = 17666;   // 5*M+2 + 2*M*S
constexpr int D1   = 770;     // 3*M+2
constexpr int D2G  = 76800;   // M * NH * NO (gat part of concat)

__device__ __forceinline__ float lrelu(float x) { return x > 0.f ? x : 0.01f * x; }
__device__ __forceinline__ float eluf(float x)  { return x > 0.f ? x : expm1f(x); }

// ---------------- K0: adjacency bitmask ----------------
__global__ __launch_bounds__(256) void k_adjmask(const int* __restrict__ adj,
                                                 unsigned* __restrict__ adjm) {
  int w = blockIdx.x * 256 + threadIdx.x;       // 2048 words: [i][8]
  if (w >= M * 8) return;
  int i = w >> 3, wd = w & 7;
  const int* row = adj + i * M + wd * 32;
  unsigned mval = 0;
  #pragma unroll
  for (int bit = 0; bit < 32; ++bit) mval |= (row[bit] > 0 ? 1u : 0u) << bit;
  adjm[w] = mval;
}

// ---------------- K1: Wh = feat @ W_gat  (+ fused e1/e2 + fused colstats) -------
// Block (b,h). After the GEMM tiles, e1/e2 for ALL m are LDS-resident, so the
// per-column softmax stats (max/sum over i) are computed here too — identical
// formula/order to the old k_colstats (same bits).
__global__ __launch_bounds__(256) void k_wh(const float* __restrict__ obs,
                                            const float* __restrict__ Wg,
                                            const float* __restrict__ ag,
                                            const unsigned* __restrict__ adjm,
                                            float* __restrict__ Wh,
                                            float* __restrict__ e1,
                                            float* __restrict__ e2,
                                            float* __restrict__ cmax,
                                            float* __restrict__ csum) {
  int b = blockIdx.x, h = blockIdx.y;
  int t = threadIdx.x;
  int to = t >> 4;          // 0..15 -> o = to*8 .. +7 (o<100 valid)
  int tm = t & 15;          // 0..15 -> m-sub = tm*8 .. +7
  __shared__ float smem_w[66 * 104 + 32];   // W[f][o], rows padded to 104
  __shared__ float featT[66 * 132];         // featT[f][m], rows padded to 132
  __shared__ float a1s[128], a2s[128];
  __shared__ float e1a[256], e2a[256];
  __shared__ unsigned ams[M * 8];           // adjacency bitmask [i][8]
  const float* ob = obs + (size_t)b * OBSD;

  for (int idx = t; idx < 66 * 104 + 32; idx += 256) {
    float v = 0.f;
    if (idx < 66 * 104) {
      int f = idx / 104, o = idx % 104;
      if (o < NO) v = Wg[((size_t)h * FIN + f) * NO + o];
    }
    smem_w[idx] = v;
  }
  if (t < 128) {
    a1s[t] = (t < NO) ? ag[h * 200 + t] : 0.f;
    a2s[t] = (t < NO) ? ag[h * 200 + NO + t] : 0.f;
  }
  for (int w = t; w < M * 8; w += 256) ams[w] = adjm[w];

  size_t basee = ((size_t)h * B + b) * M;

  for (int tile = 0; tile < 2; ++tile) {
    int m0 = tile * 128;
    if (t < 128)       featT[t]               = ob[770  + m0 + t];
    else               featT[132 + (t - 128)] = ob[1026 + m0 + (t - 128)];
    for (int idx = t; idx < 128 * 32; idx += 256) {
      int m = idx >> 5, s = idx & 31;
      featT[(2  + s) * 132 + m] = ob[1282 + (size_t)(m0 + m) * 32 + s];
      featT[(34 + s) * 132 + m] = ob[9474 + (size_t)(m0 + m) * 32 + s];
    }
    __syncthreads();

    float acc[8][8];
    #pragma unroll
    for (int q = 0; q < 8; ++q)
      #pragma unroll
      for (int p = 0; p < 8; ++p) acc[q][p] = 0.f;

    for (int f = 0; f < 66; ++f) {
      const float* fr = featT + f * 132 + tm * 8;
      const float* wr = smem_w + f * 104 + to * 8;
      float4 fa = *(const float4*)fr;
      float4 fb = *(const float4*)(fr + 4);
      float4 wa = *(const float4*)wr;
      float4 wb = *(const float4*)(wr + 4);
      float fm[8] = {fa.x, fa.y, fa.z, fa.w, fb.x, fb.y, fb.z, fb.w};
      float wv[8] = {wa.x, wa.y, wa.z, wa.w, wb.x, wb.y, wb.z, wb.w};
      #pragma unroll
      for (int q = 0; q < 8; ++q)
        #pragma unroll
        for (int p = 0; p < 8; ++p) acc[q][p] += fm[q] * wv[p];
    }
    __syncthreads();

    float* e1p = featT;              // [128][18] partials (alias featT)
    float* e2p = featT + 128 * 18;
    #pragma unroll
    for (int q = 0; q < 8; ++q) {
      float p1 = 0.f, p2 = 0.f;
      #pragma unroll
      for (int p = 0; p < 8; ++p) {
        float av = acc[q][p];
        p1 += av * a1s[to * 8 + p];
        p2 += av * a2s[to * 8 + p];
      }
      e1p[(tm * 8 + q) * 18 + to] = p1;
      e2p[(tm * 8 + q) * 18 + to] = p2;
    }

    #pragma unroll
    for (int q = 0; q < 8; ++q) {
      int m = m0 + tm * 8 + q;
      float* wp = Wh + (basee + m) * NO + to * 8;
      if (to <= 12) *(float4*)wp       = make_float4(acc[q][0], acc[q][1], acc[q][2], acc[q][3]);
      if (to <= 11) *(float4*)(wp + 4) = make_float4(acc[q][4], acc[q][5], acc[q][6], acc[q][7]);
    }
    __syncthreads();

    if (t < 128) {
      float s1 = 0.f, s2 = 0.f;
      #pragma unroll
      for (int u = 0; u < 16; ++u) {
        s1 += e1p[t * 18 + u];
        s2 += e2p[t * 18 + u];
      }
      e1[basee + m0 + t] = s1;
      e2[basee + m0 + t] = s2;
      e1a[m0 + t] = s1;
      e2a[m0 + t] = s2;
    }
    __syncthreads();
  }

  // ---- fused colstats: softmax-over-i stats for column j = t ----
  {
    float e2j = e2a[t];
    int jw = t >> 5;
    unsigned jb = 1u << (t & 31);
    float mx = -INFINITY;
    for (int i = 0; i < M; ++i) {
      float v = (ams[i * 8 + jw] & jb) ? lrelu(e1a[i] + e2j) : -9e15f;
      mx = fmaxf(mx, v);
    }
    float sm = 0.f;
    for (int i = 0; i < M; ++i) {
      float v = (ams[i * 8 + jw] & jb) ? lrelu(e1a[i] + e2j) : -9e15f;
      sm += expf(v - mx);
    }
    cmax[basee + t] = mx;
    csum[basee + t] = sm;
  }
}

// ---------------- K4: h_prime = att @ Wh (tiled GEMM), elu -> feats ----------------
// Grid (b, h, ih). Block output: 128 i-rows x 104 o-cols (100 valid).
// Per 32-j chunk: att values computed into attT[j][i] (staging threads),
// Wh chunk staged into WhC[j][o]; then 8x8 register-tile GEMM:
// 4 ds_read_b128 per 64 FMAs, distinct data per lane group.
__global__ __launch_bounds__(256) void k_attn(const float* __restrict__ Wh,
                                              const float* __restrict__ e1,
                                              const float* __restrict__ e2,
                                              const float* __restrict__ cmax,
                                              const float* __restrict__ csum,
                                              const unsigned* __restrict__ adjm,
                                              float* __restrict__ feats) {
  int b = blockIdx.x, h = blockIdx.y, ih = blockIdx.z;
  int t = threadIdx.x;
  int to = t & 15, ti = t >> 4;
  int i0 = ih * 128;
  __shared__ float WhC[32 * 104];        // 13.3 KB
  __shared__ float attT[32 * 132];       // 16.9 KB  (row stride 132: conflict-free reads)
  __shared__ float e1s[128];
  __shared__ float e2s[256], cms[256], csr[256];
  __shared__ unsigned amsT[8 * 136];     // [word][i-local]
  size_t base = ((size_t)h * B + b) * M;

  if (t < 128) e1s[t] = e1[base + i0 + t];
  e2s[t] = e2[base + t];
  cms[t] = cmax[base + t];
  csr[t] = 1.0f / csum[base + t];
  for (int idx = t; idx < 8 * 128; idx += 256) {
    int w = idx >> 7, il = idx & 127;
    amsT[w * 136 + il] = adjm[(size_t)(i0 + il) * 8 + w];
  }

  float acc[8][8];
  #pragma unroll
  for (int q = 0; q < 8; ++q)
    #pragma unroll
    for (int p = 0; p < 8; ++p) acc[q][p] = 0.f;

  const float* WhG = Wh + base * NO;
  int jp = t >> 3;            // staging: j' 0..31
  int iu = (t & 7) * 16;      // staging: 16 i's per thread

  for (int c = 0; c < 8; ++c) {
    __syncthreads();          // previous chunk fully consumed
    // stage WhC[j][o] (32 x 104, zero-padded o>=100)
    for (int idx = t; idx < 32 * 104; idx += 256) {
      int r = idx / 104, o = idx - r * 104;
      WhC[idx] = (o < NO) ? WhG[(size_t)(c * 32 + r) * NO + o] : 0.f;
    }
    // stage attT[j][i]: p = exp(masked lrelu(e1[i]+e2[j]) - cmax[j]) * rsum[j]
    {
      int jg = c * 32 + jp;
      float e2j = e2s[jg], cmj = cms[jg], rsj = csr[jg];
      unsigned wbit = 1u << (jg & 31);
      const unsigned* aw = amsT + (jg >> 5) * 136 + iu;
      const float* ep = e1s + iu;
      float* ap = attT + jp * 132 + iu;
      #pragma unroll
      for (int r = 0; r < 16; ++r) {
        float v = (aw[r] & wbit) ? lrelu(ep[r] + e2j) : -9e15f;
        ap[r] = expf(v - cmj) * rsj;
      }
    }
    __syncthreads();
    // GEMM: 32 j-steps, 8x8 per thread
    for (int j = 0; j < 32; ++j) {
      const float4* a4 = (const float4*)(attT + j * 132 + ti * 8);
      const float4* w4 = (const float4*)(WhC + j * 104 + to * 8);
      float4 aa = a4[0], ab = a4[1];
      float4 wa = w4[0], wb = w4[1];
      float av[8] = {aa.x, aa.y, aa.z, aa.w, ab.x, ab.y, ab.z, ab.w};
      float wv[8] = {wa.x, wa.y, wa.z, wa.w, wb.x, wb.y, wb.z, wb.w};
      #pragma unroll
      for (int q = 0; q < 8; ++q)
        #pragma unroll
        for (int p = 0; p < 8; ++p) acc[q][p] += av[q] * wv[p];
    }
  }

  // epilogue: elu + direct store (o-tile owned per thread; only to<13 valid)
  if (to < 13) {
    #pragma unroll
    for (int q = 0; q < 8; ++q) {
      int i = i0 + ti * 8 + q;
      float* fp = feats + ((size_t)b * M + i) * 300 + h * NO + to * 8;
      if (to < 12) {
        float4 v0 = make_float4(eluf(acc[q][0]), eluf(acc[q][1]), eluf(acc[q][2]), eluf(acc[q][3]));
        float4 v1 = make_float4(eluf(acc[q][4]), eluf(acc[q][5]), eluf(acc[q][6]), eluf(acc[q][7]));
        *(float4*)fp       = v0;
        *(float4*)(fp + 4) = v1;
      } else {  // o = 96..99 only
        fp[0] = eluf(acc[q][0]);
        fp[1] = eluf(acc[q][1]);
        fp[2] = eluf(acc[q][2]);
        fp[3] = eluf(acc[q][3]);
      }
    }
  }
}

// ---------------- K5: LN stats only (wave per row, shuffle reduce) ----------------
__global__ __launch_bounds__(256) void k_lnstats(const float* __restrict__ g,
                                                 float* __restrict__ mu_out,
                                                 float* __restrict__ rs_out) {
  int gid = blockIdx.x * 256 + threadIdx.x;
  int wid = gid >> 6, lane = gid & 63;
  const float* row = g + (size_t)wid * 300;
  float v[5];
  float s = 0.f;
  #pragma unroll
  for (int j = 0; j < 5; ++j) {
    int i = j * 64 + lane;
    v[j] = (i < 300) ? row[i] : 0.f;
    s += v[j];
  }
  #pragma unroll
  for (int d = 1; d < 64; d <<= 1) s += __shfl_xor(s, d);
  float mu = s * (1.f / 300.f);
  float ss = 0.f;
  #pragma unroll
  for (int j = 0; j < 5; ++j) {
    int i = j * 64 + lane;
    float dd = (i < 300) ? (v[j] - mu) : 0.f;
    ss += dd * dd;
  }
  #pragma unroll
  for (int d = 1; d < 64; d <<= 1) ss += __shfl_xor(ss, d);
  if (lane == 0) {
    mu_out[wid] = mu;
    rs_out[wid] = 1.0f / sqrtf(ss * (1.f / 300.f) + 1e-5f);
  }
}

// ---------------- K6: server_feat, split-F for ILP ----------------
__global__ __launch_bounds__(256) void k_sf(const float* __restrict__ obs,
                                            const float* __restrict__ W1,
                                            const float* __restrict__ b1,
                                            float* __restrict__ sf) {
  int b = blockIdx.x, t = threadIdx.x;
  int k = t & 127, fc = t >> 7;
  __shared__ float ss[D1];
  __shared__ float red[256];
  const float* ob = obs + (size_t)b * OBSD;
  for (int i = t; i < D1; i += 256) ss[i] = ob[i];
  __syncthreads();
  float acc = 0.f;
  if (k < NO) {
    int f0 = fc * 385;
    #pragma unroll 8
    for (int f = f0; f < f0 + 385; ++f) acc += ss[f] * W1[(size_t)f * NO + k];
  }
  red[t] = acc;
  __syncthreads();
  if (t < 128 && k < NO) {
    float v = red[t] + red[t + 128] + b1[k];
    sf[b * NO + k] = fmaxf(eluf(v), 0.f);
  }
}

// ---------------- K7: split-K GEMM with fused LN+elu on staging ----------------
__global__ __launch_bounds__(256) void k_gemm2(const float* __restrict__ gat,
                                               const float* __restrict__ mu,
                                               const float* __restrict__ rs,
                                               const float* __restrict__ lw,
                                               const float* __restrict__ lb,
                                               const float* __restrict__ W2,
                                               float* __restrict__ pre) {
  int bt = blockIdx.x, dc = blockIdx.y;
  int t = threadIdx.x;
  int k = t & 127, g2 = t >> 7;
  __shared__ float gt[16 * 124];
  int b0 = bt * 16, d0 = dc * 1200;
  float acc[8];
  #pragma unroll
  for (int r = 0; r < 8; ++r) acc[r] = 0.f;
  for (int ds0 = 0; ds0 < 1200; ds0 += 120) {
    int dsg = d0 + ds0;
    __syncthreads();
    for (int idx = t; idx < 16 * 120; idx += 256) {
      int rr = idx / 120, cc = idx - rr * 120;
      int gidx = dsg + cc;
      int brow = b0 + rr;
      int mrow = gidx / 300;
      int d    = gidx - mrow * 300;
      int lrow = brow * M + mrow;
      float x = gat[(size_t)brow * D2G + gidx];
      float val = (x - mu[lrow]) * rs[lrow] * lw[d] + lb[d];
      gt[rr * 124 + cc] = eluf(val);
    }
    __syncthreads();
    const float* w2p = W2 + (size_t)(100 + dsg) * 128 + k;
    for (int c4 = 0; c4 < 30; ++c4) {
      float w0  = w2p[(size_t)(c4 * 4 + 0) * 128];
      float w1  = w2p[(size_t)(c4 * 4 + 1) * 128];
      float w2v = w2p[(size_t)(c4 * 4 + 2) * 128];
      float w3  = w2p[(size_t)(c4 * 4 + 3) * 128];
      #pragma unroll
      for (int r = 0; r < 8; ++r) {
        float4 gv = *(const float4*)(gt + (g2 * 8 + r) * 124 + c4 * 4);
        acc[r] += gv.x * w0 + gv.y * w1 + gv.z * w2v + gv.w * w3;
      }
    }
  }
  #pragma unroll
  for (int r = 0; r < 8; ++r)
    pre[((size_t)dc * B + b0 + g2 * 8 + r) * 128 + k] = acc[r];
}

// ---------------- K8: hidden (+ transposed copy), split-DC ----------------
__global__ __launch_bounds__(256) void k_hid(const float* __restrict__ pre,
                                             const float* __restrict__ sf,
                                             const float* __restrict__ W2,
                                             const float* __restrict__ b2,
                                             float* __restrict__ hid,
                                             float* __restrict__ hidT) {
  int b = blockIdx.x, t = threadIdx.x;
  int k = t & 127, p = t >> 7;
  __shared__ float red[256];
  float s = 0.f;
  const float* sfb = sf + b * NO;
  #pragma unroll 4
  for (int dc = p * 32; dc < p * 32 + 32; ++dc)
    s += pre[((size_t)dc * B + b) * 128 + k];
  #pragma unroll 4
  for (int f = p * 50; f < p * 50 + 50; ++f)
    s += sfb[f] * W2[(size_t)f * 128 + k];
  red[t] = s;
  __syncthreads();
  if (t < 128) {
    float v = red[t] + red[t + 128] + b2[k];
    v = fmaxf(eluf(v), 0.f);
    hid[(size_t)b * 128 + k] = v;
    hidT[(size_t)k * B + b]  = v;
  }
}

// ---------------- K9: logits -> gumbel one-hot output ----------------
__global__ __launch_bounds__(256) void k_out(const float* __restrict__ hidT,
                                             const float* __restrict__ Wout,
                                             const float* __restrict__ bout,
                                             const float* __restrict__ ug,
                                             float* __restrict__ out) {
  int m = blockIdx.x, b = threadIdx.x;
  __shared__ float wo[128 * 36];
  for (int idx = b; idx < 128 * 36; idx += 256) {
    int kk = idx / 36, a = idx % 36;
    wo[idx] = (a < A) ? Wout[(size_t)m * 128 * A + kk * A + a] : 0.f;
  }
  __syncthreads();
  float l[36];
  #pragma unroll
  for (int a = 0; a < 36; ++a) l[a] = (a < A) ? bout[m * A + a] : 0.f;
  for (int kk = 0; kk < 128; ++kk) {
    float hv = hidT[(size_t)kk * B + b];
    const float4* w4 = (const float4*)(wo + kk * 36);
    #pragma unroll
    for (int q = 0; q < 9; ++q) {
      float4 wv = w4[q];
      l[4*q+0] += hv * wv.x;
      l[4*q+1] += hv * wv.y;
      l[4*q+2] += hv * wv.z;
      l[4*q+3] += hv * wv.w;
    }
  }
  const float* ugp = ug + ((size_t)b * M + m) * A;
  float mx = -INFINITY;
  int amx = 0;
  #pragma unroll
  for (int a = 0; a < A; ++a) {
    float th = tanhf(eluf(l[a]));
    float u = ugp[a];
    u = fminf(fmaxf(u, 1e-10f), 1.0f - 1e-10f);
    float gb = -logf(-logf(u));
    float z = th + gb;
    l[a] = z;
    if (z > mx) { mx = z; amx = a; }
  }
  float sm = 0.f;
  #pragma unroll
  for (int a = 0; a < A; ++a) { float e = expf(l[a] - mx); l[a] = e; sm += e; }
  float* op = out + ((size_t)b * M + m) * A;
  #pragma unroll
  for (int a = 0; a < A; ++a) {
    float ys = l[a] / sm;
    float yh = (a == amx) ? 1.0f : 0.0f;
    op[a] = (yh + ys) - ys;
  }
}

// ---------------- launcher ----------------
extern "C" void kernel_launch(void* const* d_in, const int* in_sizes, int n_in,
                              void* d_out, int out_size, void* d_ws, size_t ws_size,
                              hipStream_t stream) {
  const float* obs  = (const float*)d_in[0];
  const int*   adj  = (const int*)  d_in[1];
  const float* ug   = (const float*)d_in[2];
  const float* Wg   = (const float*)d_in[3];
  const float* ag   = (const float*)d_in[4];
  const float* lw   = (const float*)d_in[5];
  const float* lb   = (const float*)d_in[6];
  const float* W1   = (const float*)d_in[7];
  const float* b1   = (const float*)d_in[8];
  const float* W2   = (const float*)d_in[9];
  const float* b2   = (const float*)d_in[10];
  const float* Wout = (const float*)d_in[11];
  const float* bout = (const float*)d_in[12];
  float* out = (float*)d_out;

  float* ws = (float*)d_ws;
  size_t off = 0;
  float* Wh    = ws + off; off += (size_t)NH * B * M * NO;   // 19,660,800
  float* feats = ws + off; off += (size_t)B * M * 300;       // 19,660,800
  float* e1    = ws + off; off += (size_t)NH * B * M;
  float* e2    = ws + off; off += (size_t)NH * B * M;
  float* cmx   = ws + off; off += (size_t)NH * B * M;
  float* csm   = ws + off; off += (size_t)NH * B * M;
  float* sf    = ws + off; off += (size_t)B * NO;
  float* pre   = ws + off; off += (size_t)64 * B * 128;
  float* hid   = ws + off; off += (size_t)B * 128;
  float* hidT  = ws + off; off += (size_t)B * 128;
  float* muA   = ws + off; off += (size_t)B * M;
  float* rsA   = ws + off; off += (size_t)B * M;
  unsigned* adjm = (unsigned*)(ws + off);

  k_adjmask <<<dim3(8),         256, 0, stream>>>(adj, adjm);
  k_wh      <<<dim3(B, NH),     256, 0, stream>>>(obs, Wg, ag, adjm, Wh, e1, e2, cmx, csm);
  k_attn    <<<dim3(B, NH, 2),  256, 0, stream>>>(Wh, e1, e2, cmx, csm, adjm, feats);
  k_lnstats <<<dim3(B * M / 4), 256, 0, stream>>>(feats, muA, rsA);
  k_sf      <<<dim3(B),         256, 0, stream>>>(obs, W1, b1, sf);
  k_gemm2   <<<dim3(16, 64),    256, 0, stream>>>(feats, muA, rsA, lw, lb, W2, pre);
  k_hid     <<<dim3(B),         256, 0, stream>>>(pre, sf, W2, b2, hid, hidT);
  k_out     <<<dim3(M),         256, 0, stream>>>(hidT, Wout, bout, ug, out);
}

// Round 7
// 781.188 us; speedup vs baseline: 1.8884x; 1.0219x over previous
//
#include <hip/hip_runtime.h>
#include <math.h>

// ---------------- problem constants ----------------
constexpr int B    = 256;
constexpr int M    = 256;
constexpr int A    = 33;
constexpr int NH   = 3;
constexpr int NO   = 100;     // NOUT
constexpr int FIN  = 66;      // 2*S+2
constexpr int OBSD = 17666;   // 5*M+2 + 2*M*S
constexpr int D1   = 770;     // 3*M+2
constexpr int D2G  = 76800;   // M * NH * NO (gat part of concat)

__device__ __forceinline__ float lrelu(float x) { return x > 0.f ? x : 0.01f * x; }
__device__ __forceinline__ float eluf(float x)  { return x > 0.f ? x : expm1f(x); }

// ---------------- K0: adjacency bitmask ----------------
__global__ __launch_bounds__(256) void k_adjmask(const int* __restrict__ adj,
                                                 unsigned* __restrict__ adjm) {
  int w = blockIdx.x * 256 + threadIdx.x;       // 2048 words: [i][8]
  if (w >= M * 8) return;
  int i = w >> 3, wd = w & 7;
  const int* row = adj + i * M + wd * 32;
  unsigned mval = 0;
  #pragma unroll
  for (int bit = 0; bit < 32; ++bit) mval |= (row[bit] > 0 ? 1u : 0u) << bit;
  adjm[w] = mval;
}

// ---------------- K1: Wh = feat @ W_gat  (+ fused e1/e2 + fused colstats) -------
__global__ __launch_bounds__(256) void k_wh(const float* __restrict__ obs,
                                            const float* __restrict__ Wg,
                                            const float* __restrict__ ag,
                                            const unsigned* __restrict__ adjm,
                                            float* __restrict__ Wh,
                                            float* __restrict__ e1,
                                            float* __restrict__ e2,
                                            float* __restrict__ cmax,
                                            float* __restrict__ csum) {
  int b = blockIdx.x, h = blockIdx.y;
  int t = threadIdx.x;
  int to = t >> 4;          // 0..15 -> o = to*8 .. +7 (o<100 valid)
  int tm = t & 15;          // 0..15 -> m-sub = tm*8 .. +7
  __shared__ float smem_w[66 * 104 + 32];   // W[f][o], rows padded to 104
  __shared__ float featT[66 * 132];         // featT[f][m], rows padded to 132
  __shared__ float a1s[128], a2s[128];
  __shared__ float e1a[256], e2a[256];
  __shared__ unsigned ams[M * 8];           // adjacency bitmask [i][8]
  const float* ob = obs + (size_t)b * OBSD;

  for (int idx = t; idx < 66 * 104 + 32; idx += 256) {
    float v = 0.f;
    if (idx < 66 * 104) {
      int f = idx / 104, o = idx % 104;
      if (o < NO) v = Wg[((size_t)h * FIN + f) * NO + o];
    }
    smem_w[idx] = v;
  }
  if (t < 128) {
    a1s[t] = (t < NO) ? ag[h * 200 + t] : 0.f;
    a2s[t] = (t < NO) ? ag[h * 200 + NO + t] : 0.f;
  }
  for (int w = t; w < M * 8; w += 256) ams[w] = adjm[w];

  size_t basee = ((size_t)h * B + b) * M;

  for (int tile = 0; tile < 2; ++tile) {
    int m0 = tile * 128;
    if (t < 128)       featT[t]               = ob[770  + m0 + t];
    else               featT[132 + (t - 128)] = ob[1026 + m0 + (t - 128)];
    for (int idx = t; idx < 128 * 32; idx += 256) {
      int m = idx >> 5, s = idx & 31;
      featT[(2  + s) * 132 + m] = ob[1282 + (size_t)(m0 + m) * 32 + s];
      featT[(34 + s) * 132 + m] = ob[9474 + (size_t)(m0 + m) * 32 + s];
    }
    __syncthreads();

    float acc[8][8];
    #pragma unroll
    for (int q = 0; q < 8; ++q)
      #pragma unroll
      for (int p = 0; p < 8; ++p) acc[q][p] = 0.f;

    for (int f = 0; f < 66; ++f) {
      const float* fr = featT + f * 132 + tm * 8;
      const float* wr = smem_w + f * 104 + to * 8;
      float4 fa = *(const float4*)fr;
      float4 fb = *(const float4*)(fr + 4);
      float4 wa = *(const float4*)wr;
      float4 wb = *(const float4*)(wr + 4);
      float fm[8] = {fa.x, fa.y, fa.z, fa.w, fb.x, fb.y, fb.z, fb.w};
      float wv[8] = {wa.x, wa.y, wa.z, wa.w, wb.x, wb.y, wb.z, wb.w};
      #pragma unroll
      for (int q = 0; q < 8; ++q)
        #pragma unroll
        for (int p = 0; p < 8; ++p) acc[q][p] += fm[q] * wv[p];
    }
    __syncthreads();

    float* e1p = featT;              // [128][18] partials (alias featT)
    float* e2p = featT + 128 * 18;
    #pragma unroll
    for (int q = 0; q < 8; ++q) {
      float p1 = 0.f, p2 = 0.f;
      #pragma unroll
      for (int p = 0; p < 8; ++p) {
        float av = acc[q][p];
        p1 += av * a1s[to * 8 + p];
        p2 += av * a2s[to * 8 + p];
      }
      e1p[(tm * 8 + q) * 18 + to] = p1;
      e2p[(tm * 8 + q) * 18 + to] = p2;
    }

    #pragma unroll
    for (int q = 0; q < 8; ++q) {
      int m = m0 + tm * 8 + q;
      float* wp = Wh + (basee + m) * NO + to * 8;
      if (to <= 12) *(float4*)wp       = make_float4(acc[q][0], acc[q][1], acc[q][2], acc[q][3]);
      if (to <= 11) *(float4*)(wp + 4) = make_float4(acc[q][4], acc[q][5], acc[q][6], acc[q][7]);
    }
    __syncthreads();

    if (t < 128) {
      float s1 = 0.f, s2 = 0.f;
      #pragma unroll
      for (int u = 0; u < 16; ++u) {
        s1 += e1p[t * 18 + u];
        s2 += e2p[t * 18 + u];
      }
      e1[basee + m0 + t] = s1;
      e2[basee + m0 + t] = s2;
      e1a[m0 + t] = s1;
      e2a[m0 + t] = s2;
    }
    __syncthreads();
  }

  // ---- fused colstats: softmax-over-i stats for column j = t ----
  {
    float e2j = e2a[t];
    int jw = t >> 5;
    unsigned jb = 1u << (t & 31);
    float mx = -INFINITY;
    for (int i = 0; i < M; ++i) {
      float v = (ams[i * 8 + jw] & jb) ? lrelu(e1a[i] + e2j) : -9e15f;
      mx = fmaxf(mx, v);
    }
    float sm = 0.f;
    for (int i = 0; i < M; ++i) {
      float v = (ams[i * 8 + jw] & jb) ? lrelu(e1a[i] + e2j) : -9e15f;
      sm += expf(v - mx);
    }
    cmax[basee + t] = mx;
    csum[basee + t] = sm;
  }
}

// ---------------- K4: h_prime = att @ Wh (tiled GEMM), elu -> feats ----------------
// Grid (b, h, ih). Block: 128 i-rows x 100 o-cols. Per thread 8x8 tile with
// SPLIT o-range {to*4..+3, 64+to*4..+3}: LDS read addresses to*4 mod 32 hit
// each bank exactly 2x (free) instead of the old to*8 4-way conflict.
// WhC rows padded to 128 and zero-filled; adjm read from global (L2-hot).
__global__ __launch_bounds__(256) void k_attn(const float* __restrict__ Wh,
                                              const float* __restrict__ e1,
                                              const float* __restrict__ e2,
                                              const float* __restrict__ cmax,
                                              const float* __restrict__ csum,
                                              const unsigned* __restrict__ adjm,
                                              float* __restrict__ feats) {
  int b = blockIdx.x, h = blockIdx.y, ih = blockIdx.z;
  int t = threadIdx.x;
  int to = t & 15, ti = t >> 4;
  int i0 = ih * 128;
  __shared__ float WhC[32 * 128];        // 16 KB (cols >=100 zero)
  __shared__ float attT[32 * 132];       // 16.9 KB
  __shared__ float e1s[128];
  __shared__ float e2s[256], cms[256], csr[256];
  size_t base = ((size_t)h * B + b) * M;

  if (t < 128) e1s[t] = e1[base + i0 + t];
  e2s[t] = e2[base + t];
  cms[t] = cmax[base + t];
  csr[t] = 1.0f / csum[base + t];

  float acc[8][8];
  #pragma unroll
  for (int q = 0; q < 8; ++q)
    #pragma unroll
    for (int p = 0; p < 8; ++p) acc[q][p] = 0.f;

  const float* WhG = Wh + base * NO;
  int jp = t >> 3;            // staging: j' 0..31
  int il = (t & 7) * 16;      // staging: 16 consecutive i's per thread

  for (int c = 0; c < 8; ++c) {
    __syncthreads();          // previous chunk fully consumed
    // stage WhC[j][o] (32 x 128, zero-padded o>=100)
    for (int idx = t; idx < 32 * 128; idx += 256) {
      int r = idx >> 7, o = idx & 127;
      WhC[idx] = (o < NO) ? WhG[(size_t)(c * 32 + r) * NO + o] : 0.f;
    }
    // stage attT[j][i]: p = exp(masked lrelu(e1[i]+e2[j]) - cmax[j]) * rsum[j]
    {
      int jg = c * 32 + jp;
      float e2j = e2s[jg], cmj = cms[jg], rsj = csr[jg];
      unsigned wbit = 1u << jp;                       // jg & 31 == jp
      const unsigned* aw = adjm + (size_t)(i0 + il) * 8 + c;   // jg>>5 == c
      const float* ep = e1s + il;
      float* ap = attT + jp * 132 + il;
      #pragma unroll
      for (int r = 0; r < 16; ++r) {
        float v = (aw[r * 8] & wbit) ? lrelu(ep[r] + e2j) : -9e15f;
        ap[r] = expf(v - cmj) * rsj;
      }
    }
    __syncthreads();
    // GEMM: 32 j-steps, 8x8 per thread (split-o)
    for (int j = 0; j < 32; ++j) {
      const float4* a4 = (const float4*)(attT + j * 132 + ti * 8);
      float4 aa = a4[0], ab = a4[1];
      float4 wa = *(const float4*)(WhC + j * 128 + to * 4);
      float4 wb = *(const float4*)(WhC + j * 128 + 64 + to * 4);
      float av[8] = {aa.x, aa.y, aa.z, aa.w, ab.x, ab.y, ab.z, ab.w};
      float wv[8] = {wa.x, wa.y, wa.z, wa.w, wb.x, wb.y, wb.z, wb.w};
      #pragma unroll
      for (int q = 0; q < 8; ++q)
        #pragma unroll
        for (int p = 0; p < 8; ++p) acc[q][p] += av[q] * wv[p];
    }
  }

  // epilogue: elu + direct stores; o = to*4 (always valid), 64+to*4 (to<9)
  #pragma unroll
  for (int q = 0; q < 8; ++q) {
    int i = i0 + ti * 8 + q;
    float* fp = feats + ((size_t)b * M + i) * 300 + h * NO;
    *(float4*)(fp + to * 4) =
        make_float4(eluf(acc[q][0]), eluf(acc[q][1]), eluf(acc[q][2]), eluf(acc[q][3]));
    if (to < 9)
      *(float4*)(fp + 64 + to * 4) =
          make_float4(eluf(acc[q][4]), eluf(acc[q][5]), eluf(acc[q][6]), eluf(acc[q][7]));
  }
}

// ---------------- K5: LN stats only (wave per row, shuffle reduce) ----------------
__global__ __launch_bounds__(256) void k_lnstats(const float* __restrict__ g,
                                                 float* __restrict__ mu_out,
                                                 float* __restrict__ rs_out) {
  int gid = blockIdx.x * 256 + threadIdx.x;
  int wid = gid >> 6, lane = gid & 63;
  const float* row = g + (size_t)wid * 300;
  float v[5];
  float s = 0.f;
  #pragma unroll
  for (int j = 0; j < 5; ++j) {
    int i = j * 64 + lane;
    v[j] = (i < 300) ? row[i] : 0.f;
    s += v[j];
  }
  #pragma unroll
  for (int d = 1; d < 64; d <<= 1) s += __shfl_xor(s, d);
  float mu = s * (1.f / 300.f);
  float ss = 0.f;
  #pragma unroll
  for (int j = 0; j < 5; ++j) {
    int i = j * 64 + lane;
    float dd = (i < 300) ? (v[j] - mu) : 0.f;
    ss += dd * dd;
  }
  #pragma unroll
  for (int d = 1; d < 64; d <<= 1) ss += __shfl_xor(ss, d);
  if (lane == 0) {
    mu_out[wid] = mu;
    rs_out[wid] = 1.0f / sqrtf(ss * (1.f / 300.f) + 1e-5f);
  }
}

// ---------------- K6: server_feat, split-F for ILP ----------------
__global__ __launch_bounds__(256) void k_sf(const float* __restrict__ obs,
                                            const float* __restrict__ W1,
                                            const float* __restrict__ b1,
                                            float* __restrict__ sf) {
  int b = blockIdx.x, t = threadIdx.x;
  int k = t & 127, fc = t >> 7;
  __shared__ float ss[D1];
  __shared__ float red[256];
  const float* ob = obs + (size_t)b * OBSD;
  for (int i = t; i < D1; i += 256) ss[i] = ob[i];
  __syncthreads();
  float acc = 0.f;
  if (k < NO) {
    int f0 = fc * 385;
    #pragma unroll 8
    for (int f = f0; f < f0 + 385; ++f) acc += ss[f] * W1[(size_t)f * NO + k];
  }
  red[t] = acc;
  __syncthreads();
  if (t < 128 && k < NO) {
    float v = red[t] + red[t + 128] + b1[k];
    sf[b * NO + k] = fmaxf(eluf(v), 0.f);
  }
}

// ---------------- K7: split-K GEMM, fused LN+elu, XCD-aware block remap ----------
// Blocks sharing a W2 d-slice are mapped to the SAME XCD so the 614 KB slice
// is read into one L2 once (was: 16x from L3).
__global__ __launch_bounds__(256) void k_gemm2(const float* __restrict__ gat,
                                               const float* __restrict__ mu,
                                               const float* __restrict__ rs,
                                               const float* __restrict__ lw,
                                               const float* __restrict__ lb,
                                               const float* __restrict__ W2,
                                               float* __restrict__ pre) {
  int lid = blockIdx.y * 16 + blockIdx.x;
  int xg = lid & 7, rr0 = lid >> 3;       // xcd group, rank within group
  int dc = xg * 8 + (rr0 >> 4);           // 8 d-chunks per XCD group
  int bt = rr0 & 15;
  int t = threadIdx.x;
  int k = t & 127, g2 = t >> 7;
  __shared__ float gt[16 * 124];
  int b0 = bt * 16, d0 = dc * 1200;
  float acc[8];
  #pragma unroll
  for (int r = 0; r < 8; ++r) acc[r] = 0.f;
  for (int ds0 = 0; ds0 < 1200; ds0 += 120) {
    int dsg = d0 + ds0;
    __syncthreads();
    for (int idx = t; idx < 16 * 120; idx += 256) {
      int rr = idx / 120, cc = idx - rr * 120;
      int gidx = dsg + cc;
      int brow = b0 + rr;
      int mrow = gidx / 300;
      int d    = gidx - mrow * 300;
      int lrow = brow * M + mrow;
      float x = gat[(size_t)brow * D2G + gidx];
      float val = (x - mu[lrow]) * rs[lrow] * lw[d] + lb[d];
      gt[rr * 124 + cc] = eluf(val);
    }
    __syncthreads();
    const float* w2p = W2 + (size_t)(100 + dsg) * 128 + k;
    for (int c4 = 0; c4 < 30; ++c4) {
      float w0  = w2p[(size_t)(c4 * 4 + 0) * 128];
      float w1  = w2p[(size_t)(c4 * 4 + 1) * 128];
      float w2v = w2p[(size_t)(c4 * 4 + 2) * 128];
      float w3  = w2p[(size_t)(c4 * 4 + 3) * 128];
      #pragma unroll
      for (int r = 0; r < 8; ++r) {
        float4 gv = *(const float4*)(gt + (g2 * 8 + r) * 124 + c4 * 4);
        acc[r] += gv.x * w0 + gv.y * w1 + gv.z * w2v + gv.w * w3;
      }
    }
  }
  #pragma unroll
  for (int r = 0; r < 8; ++r)
    pre[((size_t)dc * B + b0 + g2 * 8 + r) * 128 + k] = acc[r];
}

// ---------------- K8: hidden (+ transposed copy), split-DC ----------------
__global__ __launch_bounds__(256) void k_hid(const float* __restrict__ pre,
                                             const float* __restrict__ sf,
                                             const float* __restrict__ W2,
                                             const float* __restrict__ b2,
                                             float* __restrict__ hid,
                                             float* __restrict__ hidT) {
  int b = blockIdx.x, t = threadIdx.x;
  int k = t & 127, p = t >> 7;
  __shared__ float red[256];
  float s = 0.f;
  const float* sfb = sf + b * NO;
  #pragma unroll 4
  for (int dc = p * 32; dc < p * 32 + 32; ++dc)
    s += pre[((size_t)dc * B + b) * 128 + k];
  #pragma unroll 4
  for (int f = p * 50; f < p * 50 + 50; ++f)
    s += sfb[f] * W2[(size_t)f * 128 + k];
  red[t] = s;
  __syncthreads();
  if (t < 128) {
    float v = red[t] + red[t + 128] + b2[k];
    v = fmaxf(eluf(v), 0.f);
    hid[(size_t)b * 128 + k] = v;
    hidT[(size_t)k * B + b]  = v;
  }
}

// ---------------- K9: logits -> gumbel one-hot output ----------------
__global__ __launch_bounds__(256) void k_out(const float* __restrict__ hidT,
                                             const float* __restrict__ Wout,
                                             const float* __restrict__ bout,
                                             const float* __restrict__ ug,
                                             float* __restrict__ out) {
  int m = blockIdx.x, b = threadIdx.x;
  __shared__ float wo[128 * 36];
  for (int idx = b; idx < 128 * 36; idx += 256) {
    int kk = idx / 36, a = idx % 36;
    wo[idx] = (a < A) ? Wout[(size_t)m * 128 * A + kk * A + a] : 0.f;
  }
  __syncthreads();
  float l[36];
  #pragma unroll
  for (int a = 0; a < 36; ++a) l[a] = (a < A) ? bout[m * A + a] : 0.f;
  for (int kk = 0; kk < 128; ++kk) {
    float hv = hidT[(size_t)kk * B + b];
    const float4* w4 = (const float4*)(wo + kk * 36);
    #pragma unroll
    for (int q = 0; q < 9; ++q) {
      float4 wv = w4[q];
      l[4*q+0] += hv * wv.x;
      l[4*q+1] += hv * wv.y;
      l[4*q+2] += hv * wv.z;
      l[4*q+3] += hv * wv.w;
    }
  }
  const float* ugp = ug + ((size_t)b * M + m) * A;
  float mx = -INFINITY;
  int amx = 0;
  #pragma unroll
  for (int a = 0; a < A; ++a) {
    float th = tanhf(eluf(l[a]));
    float u = ugp[a];
    u = fminf(fmaxf(u, 1e-10f), 1.0f - 1e-10f);
    float gb = -logf(-logf(u));
    float z = th + gb;
    l[a] = z;
    if (z > mx) { mx = z; amx = a; }
  }
  float sm = 0.f;
  #pragma unroll
  for (int a = 0; a < A; ++a) { float e = expf(l[a] - mx); l[a] = e; sm += e; }
  float* op = out + ((size_t)b * M + m) * A;
  #pragma unroll
  for (int a = 0; a < A; ++a) {
    float ys = l[a] / sm;
    float yh = (a == amx) ? 1.0f : 0.0f;
    op[a] = (yh + ys) - ys;
  }
}

// ---------------- launcher ----------------
extern "C" void kernel_launch(void* const* d_in, const int* in_sizes, int n_in,
                              void* d_out, int out_size, void* d_ws, size_t ws_size,
                              hipStream_t stream) {
  const float* obs  = (const float*)d_in[0];
  const int*   adj  = (const int*)  d_in[1];
  const float* ug   = (const float*)d_in[2];
  const float* Wg   = (const float*)d_in[3];
  const float* ag   = (const float*)d_in[4];
  const float* lw   = (const float*)d_in[5];
  const float* lb   = (const float*)d_in[6];
  const float* W1   = (const float*)d_in[7];
  const float* b1   = (const float*)d_in[8];
  const float* W2   = (const float*)d_in[9];
  const float* b2   = (const float*)d_in[10];
  const float* Wout = (const float*)d_in[11];
  const float* bout = (const float*)d_in[12];
  float* out = (float*)d_out;

  float* ws = (float*)d_ws;
  size_t off = 0;
  float* Wh    = ws + off; off += (size_t)NH * B * M * NO;   // 19,660,800
  float* feats = ws + off; off += (size_t)B * M * 300;       // 19,660,800
  float* e1    = ws + off; off += (size_t)NH * B * M;
  float* e2    = ws + off; off += (size_t)NH * B * M;
  float* cmx   = ws + off; off += (size_t)NH * B * M;
  float* csm   = ws + off; off += (size_t)NH * B * M;
  float* sf    = ws + off; off += (size_t)B * NO;
  float* pre   = ws + off; off += (size_t)64 * B * 128;
  float* hid   = ws + off; off += (size_t)B * 128;
  float* hidT  = ws + off; off += (size_t)B * 128;
  float* muA   = ws + off; off += (size_t)B * M;
  float* rsA   = ws + off; off += (size_t)B * M;
  unsigned* adjm = (unsigned*)(ws + off);

  k_adjmask <<<dim3(8),         256, 0, stream>>>(adj, adjm);
  k_wh      <<<dim3(B, NH),     256, 0, stream>>>(obs, Wg, ag, adjm, Wh, e1, e2, cmx, csm);
  k_attn    <<<dim3(B, NH, 2),  256, 0, stream>>>(Wh, e1, e2, cmx, csm, adjm, feats);
  k_lnstats <<<dim3(B * M / 4), 256, 0, stream>>>(feats, muA, rsA);
  k_sf      <<<dim3(B),         256, 0, stream>>>(obs, W1, b1, sf);
  k_gemm2   <<<dim3(16, 64),    256, 0, stream>>>(feats, muA, rsA, lw, lb, W2, pre);
  k_hid     <<<dim3(B),         256, 0, stream>>>(pre, sf, W2, b2, hid, hidT);
  k_out     <<<dim3(M),         256, 0, stream>>>(hidT, Wout, bout, ug, out);
}

// Round 9
// 776.959 us; speedup vs baseline: 1.8986x; 1.0054x over previous
//
#include <hip/hip_runtime.h>
#include <math.h>

// ---------------- problem constants ----------------
constexpr int B    = 256;
constexpr int M    = 256;
constexpr int A    = 33;
constexpr int NH   = 3;
constexpr int NO   = 100;     // NOUT
constexpr int FIN  = 66;      // 2*S+2
constexpr int OBSD = 17666;   // 5*M+2 + 2*M*S
constexpr int D1   = 770;     // 3*M+2
constexpr int D2G  = 76800;   // M * NH * NO (gat part of concat)

__device__ __forceinline__ float lrelu(float x) { return x > 0.f ? x : 0.01f * x; }
__device__ __forceinline__ float eluf(float x)  { return x > 0.f ? x : expm1f(x); }

// ---------------- K0: adjacency bitmask ----------------
__global__ __launch_bounds__(256) void k_adjmask(const int* __restrict__ adj,
                                                 unsigned* __restrict__ adjm) {
  int w = blockIdx.x * 256 + threadIdx.x;       // 2048 words: [i][8]
  if (w >= M * 8) return;
  int i = w >> 3, wd = w & 7;
  const int* row = adj + i * M + wd * 32;
  unsigned mval = 0;
  #pragma unroll
  for (int bit = 0; bit < 32; ++bit) mval |= (row[bit] > 0 ? 1u : 0u) << bit;
  adjm[w] = mval;
}

// ---------------- K1: Wh = feat @ W_gat  (+ fused e1/e2 + fused colstats) -------
// featT reads use SPLIT m-range {tm*4, 64+tm*4}: 2 addrs/bank = free
// (was tm*8 -> 4-way conflict on 264 b128 reads/thread).
__global__ __launch_bounds__(256) void k_wh(const float* __restrict__ obs,
                                            const float* __restrict__ Wg,
                                            const float* __restrict__ ag,
                                            const unsigned* __restrict__ adjm,
                                            float* __restrict__ Wh,
                                            float* __restrict__ e1,
                                            float* __restrict__ e2,
                                            float* __restrict__ cmax,
                                            float* __restrict__ csum) {
  int b = blockIdx.x, h = blockIdx.y;
  int t = threadIdx.x;
  int to = t >> 4;          // 0..15 -> o = to*8 .. +7 (o<100 valid)
  int tm = t & 15;          // m-quads: {tm*4..+3, 64+tm*4..+3}
  __shared__ float smem_w[66 * 104 + 32];   // W[f][o], rows padded to 104
  __shared__ float featT[66 * 132];         // featT[f][m], rows padded to 132
  __shared__ float a1s[128], a2s[128];
  __shared__ float e1a[256], e2a[256];
  __shared__ unsigned ams[M * 8];           // adjacency bitmask [i][8]
  const float* ob = obs + (size_t)b * OBSD;

  for (int idx = t; idx < 66 * 104 + 32; idx += 256) {
    float v = 0.f;
    if (idx < 66 * 104) {
      int f = idx / 104, o = idx % 104;
      if (o < NO) v = Wg[((size_t)h * FIN + f) * NO + o];
    }
    smem_w[idx] = v;
  }
  if (t < 128) {
    a1s[t] = (t < NO) ? ag[h * 200 + t] : 0.f;
    a2s[t] = (t < NO) ? ag[h * 200 + NO + t] : 0.f;
  }
  for (int w = t; w < M * 8; w += 256) ams[w] = adjm[w];

  size_t basee = ((size_t)h * B + b) * M;

  for (int tile = 0; tile < 2; ++tile) {
    int m0 = tile * 128;
    if (t < 128)       featT[t]               = ob[770  + m0 + t];
    else               featT[132 + (t - 128)] = ob[1026 + m0 + (t - 128)];
    for (int idx = t; idx < 128 * 32; idx += 256) {
      int m = idx >> 5, s = idx & 31;
      featT[(2  + s) * 132 + m] = ob[1282 + (size_t)(m0 + m) * 32 + s];
      featT[(34 + s) * 132 + m] = ob[9474 + (size_t)(m0 + m) * 32 + s];
    }
    __syncthreads();

    float acc[8][8];
    #pragma unroll
    for (int q = 0; q < 8; ++q)
      #pragma unroll
      for (int p = 0; p < 8; ++p) acc[q][p] = 0.f;

    for (int f = 0; f < 66; ++f) {
      const float* fr = featT + f * 132;
      const float* wr = smem_w + f * 104 + to * 8;
      float4 fa = *(const float4*)(fr + tm * 4);        // m = tm*4..+3
      float4 fb = *(const float4*)(fr + 64 + tm * 4);   // m = 64+tm*4..+3
      float4 wa = *(const float4*)wr;
      float4 wb = *(const float4*)(wr + 4);
      float fm[8] = {fa.x, fa.y, fa.z, fa.w, fb.x, fb.y, fb.z, fb.w};
      float wv[8] = {wa.x, wa.y, wa.z, wa.w, wb.x, wb.y, wb.z, wb.w};
      #pragma unroll
      for (int q = 0; q < 8; ++q)
        #pragma unroll
        for (int p = 0; p < 8; ++p) acc[q][p] += fm[q] * wv[p];
    }
    __syncthreads();

    float* e1p = featT;              // [128][18] partials (alias featT)
    float* e2p = featT + 128 * 18;
    #pragma unroll
    for (int q = 0; q < 8; ++q) {
      int ml = (q < 4) ? (tm * 4 + q) : (64 + tm * 4 + q - 4);
      float p1 = 0.f, p2 = 0.f;
      #pragma unroll
      for (int p = 0; p < 8; ++p) {
        float av = acc[q][p];
        p1 += av * a1s[to * 8 + p];
        p2 += av * a2s[to * 8 + p];
      }
      e1p[ml * 18 + to] = p1;
      e2p[ml * 18 + to] = p2;
    }

    #pragma unroll
    for (int q = 0; q < 8; ++q) {
      int ml = (q < 4) ? (tm * 4 + q) : (64 + tm * 4 + q - 4);
      int m = m0 + ml;
      float* wp = Wh + (basee + m) * NO + to * 8;
      if (to <= 12) *(float4*)wp       = make_float4(acc[q][0], acc[q][1], acc[q][2], acc[q][3]);
      if (to <= 11) *(float4*)(wp + 4) = make_float4(acc[q][4], acc[q][5], acc[q][6], acc[q][7]);
    }
    __syncthreads();

    if (t < 128) {
      float s1 = 0.f, s2 = 0.f;
      #pragma unroll
      for (int u = 0; u < 16; ++u) {
        s1 += e1p[t * 18 + u];
        s2 += e2p[t * 18 + u];
      }
      e1[basee + m0 + t] = s1;
      e2[basee + m0 + t] = s2;
      e1a[m0 + t] = s1;
      e2a[m0 + t] = s2;
    }
    __syncthreads();
  }

  // ---- fused colstats: softmax-over-i stats for column j = t ----
  {
    float e2j = e2a[t];
    int jw = t >> 5;
    unsigned jb = 1u << (t & 31);
    float mx = -INFINITY;
    #pragma unroll 8
    for (int i = 0; i < M; ++i) {
      float v = (ams[i * 8 + jw] & jb) ? lrelu(e1a[i] + e2j) : -9e15f;
      mx = fmaxf(mx, v);
    }
    float sm = 0.f;
    #pragma unroll 8
    for (int i = 0; i < M; ++i) {
      float v = (ams[i * 8 + jw] & jb) ? lrelu(e1a[i] + e2j) : -9e15f;
      sm += expf(v - mx);
    }
    cmax[basee + t] = mx;
    csum[basee + t] = sm;
  }
}

// ---------------- K4: h_prime = att @ Wh (tiled GEMM), elu -> feats ----------------
// Staging now STRIDED-i: thread writes i = (t&7) + 8*rr -> banks
// 4*jp + (t&7) + 8*rr = exactly 2 lanes/bank (free). Was il-contiguous ->
// all variation in bits>=2 -> 8-way (the 9.4e6 counter).
__global__ __launch_bounds__(256) void k_attn(const float* __restrict__ Wh,
                                              const float* __restrict__ e1,
                                              const float* __restrict__ e2,
                                              const float* __restrict__ cmax,
                                              const float* __restrict__ csum,
                                              const unsigned* __restrict__ adjm,
                                              float* __restrict__ feats) {
  int b = blockIdx.x, h = blockIdx.y, ih = blockIdx.z;
  int t = threadIdx.x;
  int to = t & 15, ti = t >> 4;
  int i0 = ih * 128;
  __shared__ float WhC[32 * 128];        // 16 KB (cols >=100 zero)
  __shared__ float attT[32 * 132];       // 16.9 KB
  __shared__ float e1s[128];
  __shared__ float e2s[256], cms[256], csr[256];
  size_t base = ((size_t)h * B + b) * M;

  if (t < 128) e1s[t] = e1[base + i0 + t];
  e2s[t] = e2[base + t];
  cms[t] = cmax[base + t];
  csr[t] = 1.0f / csum[base + t];

  float acc[8][8];
  #pragma unroll
  for (int q = 0; q < 8; ++q)
    #pragma unroll
    for (int p = 0; p < 8; ++p) acc[q][p] = 0.f;

  const float* WhG = Wh + base * NO;
  int jp = t >> 3;            // staging: j' 0..31
  int ib = t & 7;             // staging: i = ib + 8*rr (strided)

  for (int c = 0; c < 8; ++c) {
    __syncthreads();          // previous chunk fully consumed
    // stage WhC[j][o] (32 x 128, zero-padded o>=100)
    for (int idx = t; idx < 32 * 128; idx += 256) {
      int r = idx >> 7, o = idx & 127;
      WhC[idx] = (o < NO) ? WhG[(size_t)(c * 32 + r) * NO + o] : 0.f;
    }
    // stage attT[j][i]: p = exp(masked lrelu(e1[i]+e2[j]) - cmax[j]) * rsum[j]
    {
      int jg = c * 32 + jp;
      float e2j = e2s[jg], cmj = cms[jg], rsj = csr[jg];
      unsigned wbit = 1u << jp;                       // jg & 31 == jp
      const unsigned* aw = adjm + (size_t)(i0 + ib) * 8 + c;   // jg>>5 == c
      const float* ep = e1s + ib;
      float* ap = attT + jp * 132 + ib;
      #pragma unroll
      for (int rr = 0; rr < 16; ++rr) {
        float v = (aw[rr * 64] & wbit) ? lrelu(ep[rr * 8] + e2j) : -9e15f;
        ap[rr * 8] = expf(v - cmj) * rsj;
      }
    }
    __syncthreads();
    // GEMM: 32 j-steps, 8x8 per thread (split-o)
    for (int j = 0; j < 32; ++j) {
      const float4* a4 = (const float4*)(attT + j * 132 + ti * 8);
      float4 aa = a4[0], ab = a4[1];
      float4 wa = *(const float4*)(WhC + j * 128 + to * 4);
      float4 wb = *(const float4*)(WhC + j * 128 + 64 + to * 4);
      float av[8] = {aa.x, aa.y, aa.z, aa.w, ab.x, ab.y, ab.z, ab.w};
      float wv[8] = {wa.x, wa.y, wa.z, wa.w, wb.x, wb.y, wb.z, wb.w};
      #pragma unroll
      for (int q = 0; q < 8; ++q)
        #pragma unroll
        for (int p = 0; p < 8; ++p) acc[q][p] += av[q] * wv[p];
    }
  }

  // epilogue: elu + direct stores; o = to*4 (always valid), 64+to*4 (to<9)
  #pragma unroll
  for (int q = 0; q < 8; ++q) {
    int i = i0 + ti * 8 + q;
    float* fp = feats + ((size_t)b * M + i) * 300 + h * NO;
    *(float4*)(fp + to * 4) =
        make_float4(eluf(acc[q][0]), eluf(acc[q][1]), eluf(acc[q][2]), eluf(acc[q][3]));
    if (to < 9)
      *(float4*)(fp + 64 + to * 4) =
          make_float4(eluf(acc[q][4]), eluf(acc[q][5]), eluf(acc[q][6]), eluf(acc[q][7]));
  }
}

// ---------------- K5: LN stats only (wave per row, shuffle reduce) ----------------
__global__ __launch_bounds__(256) void k_lnstats(const float* __restrict__ g,
                                                 float* __restrict__ mu_out,
                                                 float* __restrict__ rs_out) {
  int gid = blockIdx.x * 256 + threadIdx.x;
  int wid = gid >> 6, lane = gid & 63;
  const float* row = g + (size_t)wid * 300;
  float v[5];
  float s = 0.f;
  #pragma unroll
  for (int j = 0; j < 5; ++j) {
    int i = j * 64 + lane;
    v[j] = (i < 300) ? row[i] : 0.f;
    s += v[j];
  }
  #pragma unroll
  for (int d = 1; d < 64; d <<= 1) s += __shfl_xor(s, d);
  float mu = s * (1.f / 300.f);
  float ss = 0.f;
  #pragma unroll
  for (int j = 0; j < 5; ++j) {
    int i = j * 64 + lane;
    float dd = (i < 300) ? (v[j] - mu) : 0.f;
    ss += dd * dd;
  }
  #pragma unroll
  for (int d = 1; d < 64; d <<= 1) ss += __shfl_xor(ss, d);
  if (lane == 0) {
    mu_out[wid] = mu;
    rs_out[wid] = 1.0f / sqrtf(ss * (1.f / 300.f) + 1e-5f);
  }
}

// ---------------- K7: split-K GEMM, fused LN+elu (simple mapping restored) ------
__global__ __launch_bounds__(256) void k_gemm2(const float* __restrict__ gat,
                                               const float* __restrict__ mu,
                                               const float* __restrict__ rs,
                                               const float* __restrict__ lw,
                                               const float* __restrict__ lb,
                                               const float* __restrict__ W2,
                                               float* __restrict__ pre) {
  int bt = blockIdx.x, dc = blockIdx.y;
  int t = threadIdx.x;
  int k = t & 127, g2 = t >> 7;
  __shared__ float gt[16 * 124];
  int b0 = bt * 16, d0 = dc * 1200;
  float acc[8];
  #pragma unroll
  for (int r = 0; r < 8; ++r) acc[r] = 0.f;
  for (int ds0 = 0; ds0 < 1200; ds0 += 120) {
    int dsg = d0 + ds0;
    __syncthreads();
    for (int idx = t; idx < 16 * 120; idx += 256) {
      int rr = idx / 120, cc = idx - rr * 120;
      int gidx = dsg + cc;
      int brow = b0 + rr;
      int mrow = gidx / 300;
      int d    = gidx - mrow * 300;
      int lrow = brow * M + mrow;
      float x = gat[(size_t)brow * D2G + gidx];
      float val = (x - mu[lrow]) * rs[lrow] * lw[d] + lb[d];
      gt[rr * 124 + cc] = eluf(val);
    }
    __syncthreads();
    const float* w2p = W2 + (size_t)(100 + dsg) * 128 + k;
    for (int c4 = 0; c4 < 30; ++c4) {
      float w0  = w2p[(size_t)(c4 * 4 + 0) * 128];
      float w1  = w2p[(size_t)(c4 * 4 + 1) * 128];
      float w2v = w2p[(size_t)(c4 * 4 + 2) * 128];
      float w3  = w2p[(size_t)(c4 * 4 + 3) * 128];
      #pragma unroll
      for (int r = 0; r < 8; ++r) {
        float4 gv = *(const float4*)(gt + (g2 * 8 + r) * 124 + c4 * 4);
        acc[r] += gv.x * w0 + gv.y * w1 + gv.z * w2v + gv.w * w3;
      }
    }
  }
  #pragma unroll
  for (int r = 0; r < 8; ++r)
    pre[((size_t)dc * B + b0 + g2 * 8 + r) * 128 + k] = acc[r];
}

// ---------------- K8: hidden = relu(elu(sf-part + dc-partials + b2)), sf fused ---
__global__ __launch_bounds__(256) void k_hid(const float* __restrict__ pre,
                                             const float* __restrict__ obs,
                                             const float* __restrict__ W1,
                                             const float* __restrict__ b1,
                                             const float* __restrict__ W2,
                                             const float* __restrict__ b2,
                                             float* __restrict__ hid,
                                             float* __restrict__ hidT) {
  int b = blockIdx.x, t = threadIdx.x;
  int k = t & 127, p = t >> 7;
  __shared__ float ssrv[D1];
  __shared__ float sfs[128];
  __shared__ float red[256];
  const float* ob = obs + (size_t)b * OBSD;
  for (int i = t; i < D1; i += 256) ssrv[i] = ob[i];
  __syncthreads();
  // ---- server_feat (old k_sf, identical arithmetic/order) ----
  float acc = 0.f;
  if (k < NO) {
    int f0 = p * 385;
    #pragma unroll 8
    for (int f = f0; f < f0 + 385; ++f) acc += ssrv[f] * W1[(size_t)f * NO + k];
  }
  red[t] = acc;
  __syncthreads();
  if (t < 128 && k < NO) {
    float v = red[t] + red[t + 128] + b1[k];
    sfs[k] = fmaxf(eluf(v), 0.f);
  }
  __syncthreads();
  // ---- hidden ----
  float s = 0.f;
  #pragma unroll 4
  for (int dc = p * 32; dc < p * 32 + 32; ++dc)
    s += pre[((size_t)dc * B + b) * 128 + k];
  #pragma unroll 4
  for (int f = p * 50; f < p * 50 + 50; ++f)
    s += sfs[f] * W2[(size_t)f * 128 + k];
  __syncthreads();
  red[t] = s;
  __syncthreads();
  if (t < 128) {
    float v = red[t] + red[t + 128] + b2[k];
    v = fmaxf(eluf(v), 0.f);
    hid[(size_t)b * 128 + k] = v;
    hidT[(size_t)k * B + b]  = v;
  }
}

// ---------------- K9: logits -> gumbel one-hot output ----------------
__global__ __launch_bounds__(256) void k_out(const float* __restrict__ hidT,
                                             const float* __restrict__ Wout,
                                             const float* __restrict__ bout,
                                             const float* __restrict__ ug,
                                             float* __restrict__ out) {
  int m = blockIdx.x, b = threadIdx.x;
  __shared__ float wo[128 * 36];
  for (int idx = b; idx < 128 * 36; idx += 256) {
    int kk = idx / 36, a = idx % 36;
    wo[idx] = (a < A) ? Wout[(size_t)m * 128 * A + kk * A + a] : 0.f;
  }
  __syncthreads();
  float l[36];
  #pragma unroll
  for (int a = 0; a < 36; ++a) l[a] = (a < A) ? bout[m * A + a] : 0.f;
  for (int kk = 0; kk < 128; ++kk) {
    float hv = hidT[(size_t)kk * B + b];
    const float4* w4 = (const float4*)(wo + kk * 36);
    #pragma unroll
    for (int q = 0; q < 9; ++q) {
      float4 wv = w4[q];
      l[4*q+0] += hv * wv.x;
      l[4*q+1] += hv * wv.y;
      l[4*q+2] += hv * wv.z;
      l[4*q+3] += hv * wv.w;
    }
  }
  const float* ugp = ug + ((size_t)b * M + m) * A;
  float mx = -INFINITY;
  int amx = 0;
  #pragma unroll
  for (int a = 0; a < A; ++a) {
    float th = tanhf(eluf(l[a]));
    float u = ugp[a];
    u = fminf(fmaxf(u, 1e-10f), 1.0f - 1e-10f);
    float gb = -logf(-logf(u));
    float z = th + gb;
    l[a] = z;
    if (z > mx) { mx = z; amx = a; }
  }
  float sm = 0.f;
  #pragma unroll
  for (int a = 0; a < A; ++a) { float e = expf(l[a] - mx); l[a] = e; sm += e; }
  float* op = out + ((size_t)b * M + m) * A;
  #pragma unroll
  for (int a = 0; a < A; ++a) {
    float ys = l[a] / sm;
    float yh = (a == amx) ? 1.0f : 0.0f;
    op[a] = (yh + ys) - ys;
  }
}

// ---------------- launcher ----------------
extern "C" void kernel_launch(void* const* d_in, const int* in_sizes, int n_in,
                              void* d_out, int out_size, void* d_ws, size_t ws_size,
                              hipStream_t stream) {
  const float* obs  = (const float*)d_in[0];
  const int*   adj  = (const int*)  d_in[1];
  const float* ug   = (const float*)d_in[2];
  const float* Wg   = (const float*)d_in[3];
  const float* ag   = (const float*)d_in[4];
  const float* lw   = (const float*)d_in[5];
  const float* lb   = (const float*)d_in[6];
  const float* W1   = (const float*)d_in[7];
  const float* b1   = (const float*)d_in[8];
  const float* W2   = (const float*)d_in[9];
  const float* b2   = (const float*)d_in[10];
  const float* Wout = (const float*)d_in[11];
  const float* bout = (const float*)d_in[12];
  float* out = (float*)d_out;

  float* ws = (float*)d_ws;
  size_t off = 0;
  float* Wh    = ws + off; off += (size_t)NH * B * M * NO;   // 19,660,800
  float* feats = ws + off; off += (size_t)B * M * 300;       // 19,660,800
  float* e1    = ws + off; off += (size_t)NH * B * M;
  float* e2    = ws + off; off += (size_t)NH * B * M;
  float* cmx   = ws + off; off += (size_t)NH * B * M;
  float* csm   = ws + off; off += (size_t)NH * B * M;
  float* pre   = ws + off; off += (size_t)64 * B * 128;
  float* hid   = ws + off; off += (size_t)B * 128;
  float* hidT  = ws + off; off += (size_t)B * 128;
  float* muA   = ws + off; off += (size_t)B * M;
  float* rsA   = ws + off; off += (size_t)B * M;
  unsigned* adjm = (unsigned*)(ws + off);

  k_adjmask <<<dim3(8),         256, 0, stream>>>(adj, adjm);
  k_wh      <<<dim3(B, NH),     256, 0, stream>>>(obs, Wg, ag, adjm, Wh, e1, e2, cmx, csm);
  k_attn    <<<dim3(B, NH, 2),  256, 0, stream>>>(Wh, e1, e2, cmx, csm, adjm, feats);
  k_lnstats <<<dim3(B * M / 4), 256, 0, stream>>>(feats, muA, rsA);
  k_gemm2   <<<dim3(16, 64),    256, 0, stream>>>(feats, muA, rsA, lw, lb, W2, pre);
  k_hid     <<<dim3(B),         256, 0, stream>>>(pre, obs, W1, b1, W2, b2, hid, hidT);
  k_out     <<<dim3(M),         256, 0, stream>>>(hidT, Wout, bout, ug, out);
}